// Round 1
// 1244.312 us; speedup vs baseline: 1.0554x; 1.0554x over previous
//
#include <hip/hip_runtime.h>
#include <hip/hip_bf16.h>
#include <math.h>

typedef unsigned long long ull;
typedef unsigned int uint;
typedef unsigned short ushort_t;

typedef short bf16x8 __attribute__((ext_vector_type(8)));
typedef float floatx4 __attribute__((ext_vector_type(4)));

// ---------------------------------------------------------------------------
// fp32 -> bf16 (round-to-nearest-even-ish)
// ---------------------------------------------------------------------------
__device__ inline ushort_t f2b(float f) {
    uint u = __float_as_uint(f);
    u = u + 0x7fffu + ((u >> 16) & 1u);
    return (ushort_t)(u >> 16);
}

// order-preserving bf16(bits)->uint16 map and inverse
__device__ inline uint kmap16(ushort_t u) {
    return (u & 0x8000u) ? (uint)((~u) & 0xFFFFu) : (uint)(u | 0x8000u);
}
__device__ inline ushort_t kinv16(uint k) {
    return (k & 0x8000u) ? (ushort_t)(k ^ 0x8000u) : (ushort_t)((~k) & 0xFFFFu);
}

// async 16B global -> LDS (DMA).  LDS dest = wave-uniform base + lane*16.
__device__ inline void async_copy16(const void* g, void* l) {
    __builtin_amdgcn_global_load_lds(
        (const __attribute__((address_space(1))) void*)g,
        (__attribute__((address_space(3))) void*)l, 16, 0, 0);
}

// ---------------------------------------------------------------------------
// Prep: w (300, C, 2) fp32 -> MFMA-fragment-packed bf16:
// Wb[(((c*2+t)*20 + g)*512) + lane*8 + e] = w[o=g*16+(lane&15)][ch=c*32+(lane>>4)*8+e][t]
// (zero for o>=300 or ch>=C).  Each wave's per-chunk B load is then one
// contiguous 1KB transaction instead of 16x 64B segments.
// Total size = (CP/32)*2*20*512 halves == same byte size as old layout.
// ---------------------------------------------------------------------------
__global__ void prep_w2_kernel(const float* __restrict__ w, ushort_t* __restrict__ Wb,
                               int C, int CP) {
    int CHn = CP / 32;
    int total = CHn * 2 * 20 * 512;
    for (int i = blockIdx.x * blockDim.x + threadIdx.x; i < total;
         i += gridDim.x * blockDim.x) {
        int e = i & 7;
        int lane = (i >> 3) & 63;
        int rest = i >> 9;              // (c*2+t)*20 + g
        int g = rest % 20;
        int tc = rest / 20;
        int t = tc & 1, c = tc >> 1;
        int o = g * 16 + (lane & 15);
        int ch = c * 32 + (lane >> 4) * 8 + e;
        float v = (o < 300 && ch < C) ? w[((size_t)o * C + ch) * 2 + t] : 0.f;
        Wb[i] = f2b(v);
    }
}

// bw (300,300) fp32 -> bwb[e][d] bf16 (320x320, zero pad)
__global__ void prep_bw_kernel(const float* __restrict__ bw, ushort_t* __restrict__ bwb) {
    int i = blockIdx.x * 256 + threadIdx.x;
    if (i >= 320 * 320) return;
    int e = i / 320, d = i - e * 320;
    bwb[i] = (e < 300 && d < 300) ? f2b(bw[d * 300 + e]) : (ushort_t)0;
}

// ---------------------------------------------------------------------------
// Input fp32 -> padded bf16: dst[n][r][1024], value = src row r-4 (zero pad).
// ---------------------------------------------------------------------------
__global__ __launch_bounds__(256) void x_pad_bf16_kernel(
    const float* __restrict__ src, const float* __restrict__ src2, int split_n,
    long long s_nstr, int Lin, ushort_t* __restrict__ dst, int rows)
{
    int r = blockIdx.x, n = blockIdx.y;
    const float* sp = (split_n > 0 && n >= split_n)
                          ? src2 + (size_t)(n - split_n) * s_nstr
                          : src + (size_t)n * s_nstr;
    int g = r - 4;
    ushort_t* dp = dst + ((size_t)n * rows + r) * 1024;
    int c = threadIdx.x * 4;
    ushort4 o = {0, 0, 0, 0};
    if (g >= 0 && g < Lin) {
        float4 v = *(const float4*)&sp[(size_t)g * 1024 + c];
        o.x = f2b(v.x); o.y = f2b(v.y); o.z = f2b(v.z); o.w = f2b(v.w);
    }
    *(ushort4*)&dp[c] = o;
}

// ---------------------------------------------------------------------------
// Conv GEMM, pipelined (T2+T3+T4+T5):
//  - A: 3 LDS buffers, DMA prefetch depth 2, counted s_waitcnt vmcnt(10) +
//    raw s_barrier per chunk (no vmcnt(0) drain in the loop).
//  - A LDS XOR-swizzle (slot ^= (row>>1)&3), applied via pre-swizzled global
//    source (DMA dest must stay linear) + swizzled ds_read address:
//    conflict-free ds_read_b128.
//  - B: fragment-packed layout (1KB coalesced per load), register
//    double-buffered one chunk ahead; B issued before the DMA so the
//    compiler's B-wait leaves the prefetch DMAs in flight.
//  - vmcnt accounting (per wave, per chunk): 10 B loads + 2 DMA.  At chunk-c
//    top the ops newer than DMA(c) are B_c(10)+DMA(c+1)(2) => vmcnt(10)
//    retires exactly DMA(c) in all iterations (incl. prologue/tail).
// Block: 256 thr, 4 waves; tile M=64 x N=320 (full N -> A fetched once).
// ---------------------------------------------------------------------------
template <int CP>
__global__ __launch_bounds__(256, 2) void conv_lds_kernel(
    const ushort_t* __restrict__ xq, long long xq_nstr,
    const ushort_t* __restrict__ xd, long long xd_nstr,
    const ushort_t* __restrict__ Wq, const ushort_t* __restrict__ Wd,
    const float* __restrict__ bq, const float* __restrict__ bd,
    int Lout_q, int Lout_d, int mtiles_q,
    ushort_t* __restrict__ yt)
{
    constexpr int CH = CP / 32;          // chunks (even: 32 or 10)
    constexpr int BUFB = 65 * 64;        // bytes per A buffer
    __shared__ ushort_t Abuf[3][65 * 32];

    int mt = blockIdx.x, n = blockIdx.y;
    bool isq = (n < 16);
    if (isq && mt >= mtiles_q) return;
    const ushort_t* x = isq ? xq + (size_t)n * xq_nstr
                            : xd + (size_t)(n - 16) * xd_nstr;
    const ushort_t* W = isq ? Wq : Wd;
    const float* bias = isq ? bq : bd;
    int Lout = isq ? Lout_q : Lout_d;
    int l0 = mt * 64;

    int tid = threadIdx.x, wid = tid >> 6, lane = tid & 63;
    int wn = wid * 80;
    int lrow = lane & 15, quad = lane >> 4;

    // staging: thread -> (row = tid/4, lds slot = tid%4); source slot is
    // XOR-swizzled so that LDS (row, s) holds global slot s ^ ((row>>1)&3).
    int srow = tid >> 2;
    int sslot = (tid & 3) ^ ((tid >> 3) & 3);
    const ushort_t* gMain = x + (size_t)(l0 + srow) * CP + sslot * 8;
    // extra row 64: one 16B chunk per wave (lane 0), slot = wid
    // ((64>>1)&3 == 0 so no swizzle on row 64).
    const ushort_t* gXtra = x + (size_t)(l0 + 64) * CP + wid * 8;

    // B: fragment-packed; per (c,t,ns) one contiguous 1KB block per wave.
    const ushort_t* Bw = W + ((size_t)wid * 5) * 512 + lane * 8;

    // A-fragment swizzled byte offsets (fixed per thread)
    int offA[2][4];
#pragma unroll
    for (int t = 0; t < 2; t++)
#pragma unroll
        for (int ms = 0; ms < 4; ms++) {
            int r = ms * 16 + lrow + t;
            offA[t][ms] = r * 64 + ((quad ^ ((r >> 1) & 3)) << 4);
        }

    floatx4 acc[4][5];
#pragma unroll
    for (int i = 0; i < 4; i++)
#pragma unroll
        for (int j = 0; j < 5; j++) acc[i][j] = (floatx4){0.f, 0.f, 0.f, 0.f};

    char* lds0 = (char*)&Abuf[0][0];

    auto STAGE = [&](int cc, int slot) {           // 2 vmem instrs per wave
        char* lb = lds0 + slot * BUFB;
        async_copy16(gMain + cc * 32, lb + wid * 1024);
        if (lane == 0) async_copy16(gXtra + cc * 32, lb + 4096 + wid * 16);
    };
    auto LOADB = [&](bf16x8 (&bf)[2][5], int cc) {  // 10 vmem instrs
#pragma unroll
        for (int t = 0; t < 2; t++)
#pragma unroll
            for (int ns = 0; ns < 5; ns++)
                bf[t][ns] = *(const bf16x8*)(Bw + (size_t)((cc * 2 + t) * 20 + ns) * 512);
    };
    auto COMPUTE = [&](bf16x8 (&bf)[2][5], int rslot) {
        const char* ab = lds0 + rslot * BUFB;
        __builtin_amdgcn_s_setprio(1);
#pragma unroll
        for (int t = 0; t < 2; t++) {
            bf16x8 af[4];
#pragma unroll
            for (int ms = 0; ms < 4; ms++)
                af[ms] = *(const bf16x8*)(ab + offA[t][ms]);
#pragma unroll
            for (int ms = 0; ms < 4; ms++)
#pragma unroll
                for (int ns = 0; ns < 5; ns++)
                    acc[ms][ns] = __builtin_amdgcn_mfma_f32_16x16x32_bf16(
                        af[ms], bf[t][ns], acc[ms][ns], 0, 0, 0);
        }
        __builtin_amdgcn_s_setprio(0);
    };
    auto WAITBAR = [&]() {
        // retire this chunk's DMA (oldest); leave B prefetch + next DMA in flight
        asm volatile("s_waitcnt vmcnt(10)" ::: "memory");
        __builtin_amdgcn_s_barrier();
        __builtin_amdgcn_sched_barrier(0);   // nothing crosses the barrier
    };

    bf16x8 bA[2][5], bB[2][5];

    // prologue: DMA(0), B_0, DMA(1)  (B_0 older than DMA(1) keeps it in flight)
    STAGE(0, 0);
    LOADB(bA, 0);
    STAGE(1, 1);

    int sl = 0;   // slot of chunk c (c % 3)
    for (int c = 0; c < CH; c += 2) {
        int rA = sl;
        int rB = rA + 1; if (rB == 3) rB = 0;
        int wA = rB + 1; if (wA == 3) wA = 0;   // slot (c+2)%3
        int wB = rA;                             // slot (c+3)%3

        // ---- chunk c (cur = bA) ----
        WAITBAR();
        LOADB(bB, c + 1);
        __builtin_amdgcn_sched_barrier(0x38F);   // pin VMEM order: B before DMA
        if (c + 2 < CH) STAGE(c + 2, wA);
        COMPUTE(bA, rA);

        // ---- chunk c+1 (cur = bB) ----
        WAITBAR();
        if (c + 2 < CH) LOADB(bA, c + 2);
        __builtin_amdgcn_sched_barrier(0x38F);
        if (c + 3 < CH) STAGE(c + 3, wB);
        COMPUTE(bB, rB);

        sl = wA;
    }

    ushort_t* yp = yt + (size_t)n * 488 * 320;
#pragma unroll
    for (int ns = 0; ns < 5; ns++) {
        int o = wn + ns * 16 + lrow;
        if (o >= 300) continue;
        float bo = bias[o];
#pragma unroll
        for (int ms = 0; ms < 4; ms++)
#pragma unroll
            for (int r = 0; r < 4; r++) {
                int l = l0 + ms * 16 + quad * 4 + r;
                if (l < Lout)
                    yp[(size_t)l * 320 + o] = f2b(tanhf(acc[ms][ns][r] + bo));
            }
    }
}

// ---------------------------------------------------------------------------
// 2-pass radix-select top-k on bf16 keys (k largest, ties -> smallest index).
// ---------------------------------------------------------------------------
template <int EPT>
__global__ __launch_bounds__(256) void topk16_kernel(
    const ushort_t* __restrict__ src, int CC,
    long long s_n, long long s_c, long long s_e,
    int L, int k,
    ushort_t* __restrict__ out1, long long o1_off, long long o1_n,
    long long o1_c, long long o1_e,
    ushort_t* __restrict__ out2, long long o2_off, long long o2_n,
    long long o2_c, long long o2_e)
{
    __shared__ uint sbuf[257];
    __shared__ uint wtot[4];
    __shared__ uint bsel[2];
    __shared__ uint wsum[4];

    int row = blockIdx.x;
    int n = row / CC, c = row - n * CC;
    const ushort_t* sp = src + (size_t)n * s_n + (size_t)c * s_c;

    int tid = threadIdx.x, lane = tid & 63, wid = tid >> 6;
    int base = tid * EPT;

    uint key[EPT];
    if (EPT == 4 && s_e == 1) {
        ushort4 v = *(const ushort4*)&sp[base];
        key[0] = kmap16(v.x); key[1] = kmap16(v.y);
        key[2] = kmap16(v.z); key[3] = kmap16(v.w);
    } else {
#pragma unroll
        for (int e = 0; e < EPT; e++) {
            int i = base + e;
            key[e] = (i < L) ? kmap16(sp[(size_t)i * s_e]) : 0u;
        }
    }

    uint pmask = 0, pval = 0, rem = (uint)k;
#pragma unroll
    for (int shift = 8; shift >= 0; shift -= 8) {
        sbuf[tid] = 0;
        __syncthreads();
#pragma unroll
        for (int e = 0; e < EPT; e++) {
            int i = base + e;
            if (i < L && (key[e] & pmask) == pval)
                atomicAdd(&sbuf[(key[e] >> shift) & 255], 1u);
        }
        __syncthreads();
        uint sfx = sbuf[tid];
#pragma unroll
        for (int off = 1; off < 64; off <<= 1) {
            uint u2 = __shfl_down(sfx, off);
            if (lane + off < 64) sfx += u2;
        }
        if (lane == 0) wtot[wid] = sfx;
        __syncthreads();
        uint hi = 0;
        for (int w = wid + 1; w < 4; w++) hi += wtot[w];
        sbuf[tid] = sfx + hi;             // cnt_ge[bin=tid]
        if (tid == 0) sbuf[256] = 0;
        __syncthreads();
        uint cg = sbuf[tid], cgn = sbuf[tid + 1];
        if (cg >= rem && cgn < rem) { bsel[0] = (uint)tid; bsel[1] = rem - cgn; }
        __syncthreads();
        pval |= bsel[0] << shift;
        pmask |= 0xFFu << shift;
        rem = bsel[1];
        __syncthreads();
    }

    const uint T = pval;
    uint gtc = 0, eqc = 0;
#pragma unroll
    for (int e = 0; e < EPT; e++) {
        int i = base + e;
        if (i < L) {
            gtc += (key[e] > T) ? 1u : 0u;
            eqc += (key[e] == T) ? 1u : 0u;
        }
    }
    uint pack = (gtc << 16) | eqc;
    uint incl = pack;
#pragma unroll
    for (int off = 1; off < 64; off <<= 1) {
        uint u2 = __shfl_up(incl, off);
        if (lane >= off) incl += u2;
    }
    uint excl = incl - pack;
    if (lane == 63) wsum[wid] = incl;
    __syncthreads();
    uint badd = 0;
    for (int w = 0; w < wid; w++) badd += wsum[w];
    excl += badd;
    uint gt_before = excl >> 16, eq_before = excl & 0xffffu;

    ushort_t* dp1 = out1 + (size_t)o1_off + (size_t)n * o1_n + (size_t)c * o1_c;
    ushort_t* dp2 = out2 ? out2 + (size_t)o2_off + (size_t)n * o2_n + (size_t)c * o2_c
                         : (ushort_t*)0;
#pragma unroll
    for (int e = 0; e < EPT; e++) {
        int i = base + e;
        if (i >= L) break;
        uint kk = key[e];
        if (kk > T) {
            uint pos = gt_before + (eq_before < rem ? eq_before : rem);
            ushort_t v = kinv16(kk);
            dp1[(size_t)pos * o1_e] = v;
            if (dp2) dp2[(size_t)pos * o2_e] = v;
            gt_before++;
        } else if (kk == T) {
            if (eq_before < rem) {
                uint pos = gt_before + eq_before;
                ushort_t v = kinv16(kk);
                dp1[(size_t)pos * o1_e] = v;
                if (dp2) dp2[(size_t)pos * o2_e] = v;
            }
            eq_before++;
        }
    }
}

// ---------------------------------------------------------------------------
// qt GEMM: qtb[b,m,e] = bf16( sum_d qgb[b,m,d] * bwb[e,d] ).
// ---------------------------------------------------------------------------
__global__ __launch_bounds__(256) void qt_mfma_kernel(
    const ushort_t* __restrict__ qgb, const ushort_t* __restrict__ bwb,
    ushort_t* __restrict__ qtb)
{
    int mt = blockIdx.x, b = blockIdx.y;
    int tid = threadIdx.x, wid = tid >> 6, lane = tid & 63;
    int wn = wid * 80, lrow = lane & 15, quad = lane >> 4;

    const ushort_t* A = qgb + ((size_t)b * 480 + mt * 48 + lrow) * 320 + quad * 8;
    const ushort_t* B = bwb + (size_t)(wn + lrow) * 320 + quad * 8;

    floatx4 acc[3][5];
#pragma unroll
    for (int i = 0; i < 3; i++)
#pragma unroll
        for (int j = 0; j < 5; j++) acc[i][j] = (floatx4){0.f, 0.f, 0.f, 0.f};

#pragma unroll 5
    for (int c0 = 0; c0 < 320; c0 += 32) {
        bf16x8 af[3], bfr[5];
#pragma unroll
        for (int ms = 0; ms < 3; ms++)
            af[ms] = *(const bf16x8*)&A[(size_t)(ms * 16) * 320 + c0];
#pragma unroll
        for (int ns = 0; ns < 5; ns++)
            bfr[ns] = *(const bf16x8*)&B[(size_t)(ns * 16) * 320 + c0];
#pragma unroll
        for (int ms = 0; ms < 3; ms++)
#pragma unroll
            for (int ns = 0; ns < 5; ns++)
                acc[ms][ns] = __builtin_amdgcn_mfma_f32_16x16x32_bf16(
                    af[ms], bfr[ns], acc[ms][ns], 0, 0, 0);
    }

    ushort_t* out = qtb + ((size_t)b * 480 + mt * 48) * 320;
#pragma unroll
    for (int ms = 0; ms < 3; ms++)
#pragma unroll
        for (int ns = 0; ns < 5; ns++)
#pragma unroll
            for (int r = 0; r < 4; r++)
                out[(size_t)(ms * 16 + quad * 4 + r) * 320 + wn + ns * 16 + lrow] =
                    f2b(acc[ms][ns][r]);
}

// ---------------------------------------------------------------------------
// MFMA M-GEMM fused with pooling.
// ---------------------------------------------------------------------------
__global__ __launch_bounds__(256) void mpool_mfma_kernel(
    const ushort_t* __restrict__ qtb16, const ushort_t* __restrict__ dgb16,
    const float* __restrict__ bb, float* __restrict__ mp)
{
    __shared__ float pool[2 * 12 * 192];

    int jb = blockIdx.x;
    int qb = blockIdx.y;
    int n  = blockIdx.z;
    int b  = n & 15;

    int tid = threadIdx.x;
    int wid = tid >> 6, lane = tid & 63;
    int wm2 = wid >> 1;
    int wm = wm2 * 48, wn = (wid & 1) * 96;
    int lrow = lane & 15, quad = lane >> 4;

    const ushort_t* Abase = qtb16 + ((size_t)b * 480 + qb * 96 + wm) * 320 + quad * 8;
    const ushort_t* Bbase = dgb16 + ((size_t)n * 960 + jb * 192 + wn) * 320 + quad * 8;

    floatx4 acc[3][6];
#pragma unroll
    for (int i = 0; i < 3; i++)
#pragma unroll
        for (int j = 0; j < 6; j++) acc[i][j] = (floatx4){0.f, 0.f, 0.f, 0.f};

#pragma unroll 2
    for (int c0 = 0; c0 < 320; c0 += 32) {
        bf16x8 af[3], bfr[6];
#pragma unroll
        for (int mt = 0; mt < 3; mt++)
            af[mt] = *(const bf16x8*)&Abase[(size_t)(mt * 16 + lrow) * 320 + c0];
#pragma unroll
        for (int nt = 0; nt < 6; nt++)
            bfr[nt] = *(const bf16x8*)&Bbase[(size_t)(nt * 16 + lrow) * 320 + c0];
#pragma unroll
        for (int mt = 0; mt < 3; mt++)
#pragma unroll
            for (int nt = 0; nt < 6; nt++)
                acc[mt][nt] = __builtin_amdgcn_mfma_f32_16x16x32_bf16(
                    af[mt], bfr[nt], acc[mt][nt], 0, 0, 0);
    }

#pragma unroll
    for (int mt = 0; mt < 3; mt++) {
        int g = mt * 4 + quad;
#pragma unroll
        for (int nt = 0; nt < 6; nt++) {
            floatx4 a = acc[mt][nt];
            float rm = fmaxf(fmaxf(a[0], a[1]), fmaxf(a[2], a[3]));
            pool[(wm2 * 12 + g) * 192 + wn + nt * 16 + lrow] = rm;
        }
    }
    __syncthreads();

    if (tid < 64) {
        int qw = tid >> 3, jw = tid & 7;
        int slab = qw >> 2, w = qw & 3;
        float m = -INFINITY;
        const float* pp = &pool[(slab * 12 + w * 3) * 192 + jw * 24];
        for (int g = 0; g < 3; g++)
            for (int cc = 0; cc < 24; cc++)
                m = fmaxf(m, pp[g * 192 + cc]);
        float sig = 1.f / (1.f + expf(-(m + bb[0])));
        mp[(size_t)n * 1600 + (size_t)(qb * 8 + qw) * 40 + (jb * 8 + jw)] = sig;
    }
}

// ---------------------------------------------------------------------------
// Conv block, channel-parallel, atomicMax-merged (Y zeroed before launch).
// ---------------------------------------------------------------------------
#define OCG 10
__global__ __launch_bounds__(256) void convblock_atomic_kernel(
    const float* __restrict__ X, const float* __restrict__ w,
    const float* __restrict__ bias, uint* __restrict__ Y)
{
    __shared__ float xp[48 * 48];
    __shared__ float ys[47 * 47];
    __shared__ float t1[40 * 47];
    __shared__ float outacc[1600];

    int n = blockIdx.x, t = threadIdx.x;
    int oc0 = blockIdx.y * OCG;
    const float* xn = X + (size_t)n * 1600;
    for (int i = t; i < 48 * 48; i += 256) {
        int r = i / 48, c = i - r * 48;
        int rr = r - 4, cc = c - 4;
        xp[i] = (rr >= 0 && rr < 40 && cc >= 0 && cc < 40) ? xn[rr * 40 + cc] : 0.f;
    }
    for (int i = t; i < 1600; i += 256) outacc[i] = 0.f;
    __syncthreads();

    for (int oc = oc0; oc < oc0 + OCG; oc++) {
        float w00 = w[oc * 4 + 0], w01 = w[oc * 4 + 1];
        float w10 = w[oc * 4 + 2], w11 = w[oc * 4 + 3];
        float bo = bias[oc];
        for (int i = t; i < 47 * 47; i += 256) {
            int r = i / 47, c = i - r * 47;
            float v = xp[r * 48 + c] * w00 + xp[r * 48 + c + 1] * w01
                    + xp[(r + 1) * 48 + c] * w10 + xp[(r + 1) * 48 + c + 1] * w11 + bo;
            ys[i] = 1.f / (1.f + expf(-v));
        }
        __syncthreads();
        for (int i = t; i < 40 * 47; i += 256) {
            int r = i / 47, c = i - r * 47;
            int s = (47 * r) / 40, e = (47 * (r + 1) + 39) / 40;
            float m = ys[s * 47 + c];
            for (int x = s + 1; x < e; x++) m = fmaxf(m, ys[x * 47 + c]);
            t1[i] = m;
        }
        __syncthreads();
        for (int i = t; i < 1600; i += 256) {
            int r = i / 40, c = i - r * 40;
            int s = (47 * c) / 40, e = (47 * (c + 1) + 39) / 40;
            float m = t1[r * 47 + s];
            for (int x = s + 1; x < e; x++) m = fmaxf(m, t1[r * 47 + x]);
            outacc[i] = fmaxf(outacc[i], m);
        }
        __syncthreads();
    }
    for (int i = t; i < 1600; i += 256)
        atomicMax(&Y[(size_t)n * 1600 + i], __float_as_uint(outacc[i]));
}

// ---------------------------------------------------------------------------
// Head
// ---------------------------------------------------------------------------
__global__ __launch_bounds__(64) void head_kernel(
    const float* __restrict__ feat, const float* __restrict__ lw,
    const float* __restrict__ lb, float* __restrict__ out)
{
    __shared__ float hs[40];
    int n = blockIdx.x, t = threadIdx.x;
    const float* f = feat + (size_t)n * 1600;
    if (t < 40) {
        float a = 0.f;
        for (int j = 0; j < 40; j++) a += f[t * 40 + j] * lw[j];
        hs[t] = 1.f / (1.f + expf(-(a + lb[0])));
    }
    __syncthreads();
    if (t == 0) {
        float a = 0.f;
        for (int i = 0; i < 40; i++) a += hs[i] * lw[i];
        out[n] = 1.f / (1.f + expf(-(a + lb[0])));
    }
}

// ---------------------------------------------------------------------------
extern "C" void kernel_launch(void* const* d_in, const int* in_sizes, int n_in,
                              void* d_out, int out_size, void* d_ws, size_t ws_size,
                              hipStream_t stream) {
    const float* query    = (const float*)d_in[0];
    const float* pos_doc  = (const float*)d_in[1];
    const float* neg_docs = (const float*)d_in[2];
    const float* qw1 = (const float*)d_in[3];  const float* qb1 = (const float*)d_in[4];
    const float* qw2 = (const float*)d_in[5];  const float* qb2 = (const float*)d_in[6];
    const float* qw3 = (const float*)d_in[7];  const float* qb3 = (const float*)d_in[8];
    const float* dw1 = (const float*)d_in[9];  const float* db1 = (const float*)d_in[10];
    const float* dw2 = (const float*)d_in[11]; const float* db2 = (const float*)d_in[12];
    const float* dw3 = (const float*)d_in[13]; const float* db3 = (const float*)d_in[14];
    const float* bw  = (const float*)d_in[15]; const float* bb  = (const float*)d_in[16];
    const float* mw1 = (const float*)d_in[17]; const float* mb1 = (const float*)d_in[18];
    const float* mw2 = (const float*)d_in[19]; const float* mb2 = (const float*)d_in[20];
    const float* mw3 = (const float*)d_in[21]; const float* mb3 = (const float*)d_in[22];
    const float* lw  = (const float*)d_in[23]; const float* lb  = (const float*)d_in[24];

    float* ws = (float*)d_ws;
    // ---- layout (float offsets) ----
    ushort_t* qw1b  = (ushort_t*)(ws + 0);          // 320*2048 bf16
    ushort_t* qw2b  = (ushort_t*)(ws + 327680);     // 320*640
    ushort_t* qw3b  = (ushort_t*)(ws + 430080);
    ushort_t* dw1b  = (ushort_t*)(ws + 532480);
    ushort_t* dw2b  = (ushort_t*)(ws + 860160);
    ushort_t* dw3b  = (ushort_t*)(ws + 962560);
    ushort_t* bwb   = (ushort_t*)(ws + 1064960);    // 320*320
    ushort_t* qgb16 = (ushort_t*)(ws + 1116160);    // (16,480,320)
    ushort_t* dgb16 = (ushort_t*)(ws + 2344960);    // (80,960,320)
    ushort_t* yt    = (ushort_t*)(ws + 14632960);   // (96,488,320)
    ushort_t* qxb   = (ushort_t*)(ws + 22128640);   // (16,264,1024)
    ushort_t* p1q   = (ushort_t*)(ws + 22128640);   // (16,200,320)
    ushort_t* p2q   = (ushort_t*)(ws + 22640640);   // (16,104,320)
    ushort_t* dxb   = (ushort_t*)(ws + 24291328);   // (80,520,1024)
    ushort_t* p1d   = (ushort_t*)(ws + 24291328);   // (80,360,320)
    ushort_t* p2d   = (ushort_t*)(ws + 28899328);   // (80,200,320)
    ushort_t* qtb16 = (ushort_t*)(ws + 31459328);   // (16,480,320)
    float*    mp    = ws + 32688128;                // (80,40,40)
    float*    ya    = ws + 32816128;                // (80,40,40)
    float*    yb    = ws + 32944128;                // (80,40,40)
    float*    yc    = ws + 33072128;                // (80,40,40)

    // ---- weight prep (MFMA-fragment-packed layout) ----
    prep_w2_kernel<<<1280, 256, 0, stream>>>(qw1, qw1b, 1024, 1024);
    prep_w2_kernel<<<400, 256, 0, stream>>>(qw2, qw2b, 300, 320);
    prep_w2_kernel<<<400, 256, 0, stream>>>(qw3, qw3b, 300, 320);
    prep_w2_kernel<<<1280, 256, 0, stream>>>(dw1, dw1b, 1024, 1024);
    prep_w2_kernel<<<400, 256, 0, stream>>>(dw2, dw2b, 300, 320);
    prep_w2_kernel<<<400, 256, 0, stream>>>(dw3, dw3b, 300, 320);
    prep_bw_kernel<<<400, 256, 0, stream>>>(bw, bwb);

    // ---- input convert to padded bf16 ----
    {
        dim3 g(264, 16);
        x_pad_bf16_kernel<<<g, 256, 0, stream>>>(query, nullptr, 0,
                                                 239LL * 1024, 239, qxb, 264);
    }
    {
        dim3 g(520, 80);
        x_pad_bf16_kernel<<<g, 256, 0, stream>>>(pos_doc, neg_docs, 16,
                                                 479LL * 1024, 479, dxb, 520);
    }

    // ---- g0 top-ks ----
    topk16_kernel<4><<<16 * 239, 256, 0, stream>>>(
        qxb + 4 * 1024, 239, 264LL * 1024, 1024, 1, 1024, 300,
        qgb16, 0, 480LL * 320, 320, 1,
        nullptr, 0, 0, 0, 0);
    topk16_kernel<4><<<80 * 479, 256, 0, stream>>>(
        dxb + 4 * 1024, 479, 520LL * 1024, 1024, 1, 1024, 300,
        dgb16, 0, 960LL * 320, 320, 1,
        nullptr, 0, 0, 0, 0);

    // ---- conv1 (pipelined LDS conv, full N per block) ----
    {
        dim3 g(8, 96);
        conv_lds_kernel<1024><<<g, 256, 0, stream>>>(
            qxb, 264LL * 1024, dxb, 520LL * 1024,
            qw1b, dw1b, qb1, db1, 246, 486, 4, yt);
    }

    // ---- zero conv2/3 input pads ----
    hipMemsetAsync(p1q, 0, 16 * 200 * 320 * 2, stream);
    hipMemsetAsync(p2q, 0, 16 * 104 * 320 * 2, stream);
    hipMemsetAsync(p1d, 0, (size_t)80 * 360 * 320 * 2, stream);
    hipMemsetAsync(p2d, 0, (size_t)80 * 200 * 320 * 2, stream);
    // ---- zero conv-block outputs (atomicMax targets) ----
    hipMemsetAsync(ya, 0, 80 * 1600 * 4, stream);
    hipMemsetAsync(yb, 0, 80 * 1600 * 4, stream);
    hipMemsetAsync(yc, 0, 80 * 1600 * 4, stream);

    // ---- p1 top-ks ----
    topk16_kernel<1><<<16 * 300, 256, 0, stream>>>(
        yt, 300, 488LL * 320, 1, 320, 246, 160,
        qgb16, 239LL * 320, 480LL * 320, 1, 320,
        p1q, 4LL * 320, 200LL * 320, 1, 320);
    topk16_kernel<2><<<80 * 300, 256, 0, stream>>>(
        yt + (size_t)16 * 488 * 320, 300, 488LL * 320, 1, 320, 486, 320,
        dgb16, 479LL * 320, 960LL * 320, 1, 320,
        p1d, 4LL * 320, 360LL * 320, 1, 320);

    // ---- conv2 ----
    {
        dim3 g(6, 96);
        conv_lds_kernel<320><<<g, 256, 0, stream>>>(
            p1q, 200LL * 320, p1d, 360LL * 320,
            qw2b, dw2b, qb2, db2, 167, 327, 3, yt);
    }

    // ---- p2 top-ks ----
    topk16_kernel<1><<<16 * 300, 256, 0, stream>>>(
        yt, 300, 488LL * 320, 1, 320, 167, 80,
        qgb16, 399LL * 320, 480LL * 320, 1, 320,
        p2q, 4LL * 320, 104LL * 320, 1, 320);
    topk16_kernel<2><<<80 * 300, 256, 0, stream>>>(
        yt + (size_t)16 * 488 * 320, 300, 488LL * 320, 1, 320, 327, 160,
        dgb16, 799LL * 320, 960LL * 320, 1, 320,
        p2d, 4LL * 320, 200LL * 320, 1, 320);

    // ---- conv3 ----
    {
        dim3 g(3, 96);
        conv_lds_kernel<320><<<g, 256, 0, stream>>>(
            p2q, 104LL * 320, p2d, 200LL * 320,
            qw3b, dw3b, qb3, db3, 87, 167, 2, yt);
    }

    // ---- p3 top-ks ----
    topk16_kernel<1><<<16 * 300, 256, 0, stream>>>(
        yt, 300, 488LL * 320, 1, 320, 87, 1,
        qgb16, 479LL * 320, 480LL * 320, 1, 320,
        nullptr, 0, 0, 0, 0);
    topk16_kernel<1><<<80 * 300, 256, 0, stream>>>(
        yt + (size_t)16 * 488 * 320, 300, 488LL * 320, 1, 320, 167, 1,
        dgb16, 959LL * 320, 960LL * 320, 1, 320,
        nullptr, 0, 0, 0, 0);

    // ---- qt GEMM + fused similarity/pool ----
    {
        dim3 g(10, 16);
        qt_mfma_kernel<<<g, 256, 0, stream>>>(qgb16, bwb, qtb16);
    }
    {
        dim3 g(5, 5, 80);
        mpool_mfma_kernel<<<g, 256, 0, stream>>>(qtb16, dgb16, bb, mp);
    }

    // ---- conv blocks (channel-parallel, atomicMax-merged) + head ----
    {
        dim3 g(80, 5);
        convblock_atomic_kernel<<<g, 256, 0, stream>>>(mp, mw1, mb1, (uint*)ya);
        convblock_atomic_kernel<<<g, 256, 0, stream>>>(ya, mw2, mb2, (uint*)yb);
        convblock_atomic_kernel<<<g, 256, 0, stream>>>(yb, mw3, mb3, (uint*)yc);
    }
    head_kernel<<<80, 64, 0, stream>>>(yc, lw, lb, (float*)d_out);
}

// Round 2
// 1131.862 us; speedup vs baseline: 1.1603x; 1.0993x over previous
//
#include <hip/hip_runtime.h>
#include <hip/hip_bf16.h>
#include <math.h>

typedef unsigned long long ull;
typedef unsigned int uint;
typedef unsigned short ushort_t;

typedef short bf16x8 __attribute__((ext_vector_type(8)));
typedef float floatx4 __attribute__((ext_vector_type(4)));

// ---------------------------------------------------------------------------
// fp32 -> bf16 (round-to-nearest-even-ish)
// ---------------------------------------------------------------------------
__device__ inline ushort_t f2b(float f) {
    uint u = __float_as_uint(f);
    u = u + 0x7fffu + ((u >> 16) & 1u);
    return (ushort_t)(u >> 16);
}

// order-preserving bf16(bits)->uint16 map and inverse
__device__ inline uint kmap16(ushort_t u) {
    return (u & 0x8000u) ? (uint)((~u) & 0xFFFFu) : (uint)(u | 0x8000u);
}
__device__ inline ushort_t kinv16(uint k) {
    return (k & 0x8000u) ? (ushort_t)(k ^ 0x8000u) : (ushort_t)((~k) & 0xFFFFu);
}

// async 16B global -> LDS (DMA).  LDS dest = wave-uniform base + lane*16.
__device__ inline void async_copy16(const void* g, void* l) {
    __builtin_amdgcn_global_load_lds(
        (const __attribute__((address_space(1))) void*)g,
        (__attribute__((address_space(3))) void*)l, 16, 0, 0);
}

// ---------------------------------------------------------------------------
// Prep: w (300, C, 2) fp32 -> MFMA-fragment-packed bf16:
// Wb[(((c*2+t)*20 + g)*512) + lane*8 + e] = w[o=g*16+(lane&15)][ch=c*32+(lane>>4)*8+e][t]
// ---------------------------------------------------------------------------
__global__ void prep_w2_kernel(const float* __restrict__ w, ushort_t* __restrict__ Wb,
                               int C, int CP) {
    int CHn = CP / 32;
    int total = CHn * 2 * 20 * 512;
    for (int i = blockIdx.x * blockDim.x + threadIdx.x; i < total;
         i += gridDim.x * blockDim.x) {
        int e = i & 7;
        int lane = (i >> 3) & 63;
        int rest = i >> 9;              // (c*2+t)*20 + g
        int g = rest % 20;
        int tc = rest / 20;
        int t = tc & 1, c = tc >> 1;
        int o = g * 16 + (lane & 15);
        int ch = c * 32 + (lane >> 4) * 8 + e;
        float v = (o < 300 && ch < C) ? w[((size_t)o * C + ch) * 2 + t] : 0.f;
        Wb[i] = f2b(v);
    }
}

// bw (300,300) fp32 -> bwb[e][d] bf16 (320x320, zero pad)
__global__ void prep_bw_kernel(const float* __restrict__ bw, ushort_t* __restrict__ bwb) {
    int i = blockIdx.x * 256 + threadIdx.x;
    if (i >= 320 * 320) return;
    int e = i / 320, d = i - e * 320;
    bwb[i] = (e < 300 && d < 300) ? f2b(bw[d * 300 + e]) : (ushort_t)0;
}

// ---------------------------------------------------------------------------
// Input fp32 -> padded bf16: dst[n][r][1024], value = src row r-4 (zero pad).
// ---------------------------------------------------------------------------
__global__ __launch_bounds__(256) void x_pad_bf16_kernel(
    const float* __restrict__ src, const float* __restrict__ src2, int split_n,
    long long s_nstr, int Lin, ushort_t* __restrict__ dst, int rows)
{
    int r = blockIdx.x, n = blockIdx.y;
    const float* sp = (split_n > 0 && n >= split_n)
                          ? src2 + (size_t)(n - split_n) * s_nstr
                          : src + (size_t)n * s_nstr;
    int g = r - 4;
    ushort_t* dp = dst + ((size_t)n * rows + r) * 1024;
    int c = threadIdx.x * 4;
    ushort4 o = {0, 0, 0, 0};
    if (g >= 0 && g < Lin) {
        float4 v = *(const float4*)&sp[(size_t)g * 1024 + c];
        o.x = f2b(v.x); o.y = f2b(v.y); o.z = f2b(v.z); o.w = f2b(v.w);
    }
    *(ushort4*)&dp[c] = o;
}

// ---------------------------------------------------------------------------
// Conv GEMM, pipelined (T2+T3+T4+T5).  Output TRANSPOSED: yt2[n][o=320][l=488]
// so that the downstream per-channel top-k reads a contiguous row.
// ---------------------------------------------------------------------------
template <int CP>
__global__ __launch_bounds__(256, 2) void conv_lds_kernel(
    const ushort_t* __restrict__ xq, long long xq_nstr,
    const ushort_t* __restrict__ xd, long long xd_nstr,
    const ushort_t* __restrict__ Wq, const ushort_t* __restrict__ Wd,
    const float* __restrict__ bq, const float* __restrict__ bd,
    int Lout_q, int Lout_d, int mtiles_q,
    ushort_t* __restrict__ yt)
{
    constexpr int CH = CP / 32;          // chunks (even: 32 or 10)
    constexpr int BUFB = 65 * 64;        // bytes per A buffer
    __shared__ ushort_t Abuf[3][65 * 32];

    int mt = blockIdx.x, n = blockIdx.y;
    bool isq = (n < 16);
    if (isq && mt >= mtiles_q) return;
    const ushort_t* x = isq ? xq + (size_t)n * xq_nstr
                            : xd + (size_t)(n - 16) * xd_nstr;
    const ushort_t* W = isq ? Wq : Wd;
    const float* bias = isq ? bq : bd;
    int Lout = isq ? Lout_q : Lout_d;
    int l0 = mt * 64;

    int tid = threadIdx.x, wid = tid >> 6, lane = tid & 63;
    int wn = wid * 80;
    int lrow = lane & 15, quad = lane >> 4;

    // staging: thread -> (row = tid/4, lds slot = tid%4); source slot is
    // XOR-swizzled so that LDS (row, s) holds global slot s ^ ((row>>1)&3).
    int srow = tid >> 2;
    int sslot = (tid & 3) ^ ((tid >> 3) & 3);
    const ushort_t* gMain = x + (size_t)(l0 + srow) * CP + sslot * 8;
    const ushort_t* gXtra = x + (size_t)(l0 + 64) * CP + wid * 8;

    // B: fragment-packed; per (c,t,ns) one contiguous 1KB block per wave.
    const ushort_t* Bw = W + ((size_t)wid * 5) * 512 + lane * 8;

    // A-fragment swizzled byte offsets (fixed per thread)
    int offA[2][4];
#pragma unroll
    for (int t = 0; t < 2; t++)
#pragma unroll
        for (int ms = 0; ms < 4; ms++) {
            int r = ms * 16 + lrow + t;
            offA[t][ms] = r * 64 + ((quad ^ ((r >> 1) & 3)) << 4);
        }

    floatx4 acc[4][5];
#pragma unroll
    for (int i = 0; i < 4; i++)
#pragma unroll
        for (int j = 0; j < 5; j++) acc[i][j] = (floatx4){0.f, 0.f, 0.f, 0.f};

    char* lds0 = (char*)&Abuf[0][0];

    auto STAGE = [&](int cc, int slot) {           // 2 vmem instrs per wave
        char* lb = lds0 + slot * BUFB;
        async_copy16(gMain + cc * 32, lb + wid * 1024);
        if (lane == 0) async_copy16(gXtra + cc * 32, lb + 4096 + wid * 16);
    };
    auto LOADB = [&](bf16x8 (&bf)[2][5], int cc) {  // 10 vmem instrs
#pragma unroll
        for (int t = 0; t < 2; t++)
#pragma unroll
            for (int ns = 0; ns < 5; ns++)
                bf[t][ns] = *(const bf16x8*)(Bw + (size_t)((cc * 2 + t) * 20 + ns) * 512);
    };
    auto COMPUTE = [&](bf16x8 (&bf)[2][5], int rslot) {
        const char* ab = lds0 + rslot * BUFB;
        __builtin_amdgcn_s_setprio(1);
#pragma unroll
        for (int t = 0; t < 2; t++) {
            bf16x8 af[4];
#pragma unroll
            for (int ms = 0; ms < 4; ms++)
                af[ms] = *(const bf16x8*)(ab + offA[t][ms]);
#pragma unroll
            for (int ms = 0; ms < 4; ms++)
#pragma unroll
                for (int ns = 0; ns < 5; ns++)
                    acc[ms][ns] = __builtin_amdgcn_mfma_f32_16x16x32_bf16(
                        af[ms], bf[t][ns], acc[ms][ns], 0, 0, 0);
        }
        __builtin_amdgcn_s_setprio(0);
    };
    auto WAITBAR = [&]() {
        asm volatile("s_waitcnt vmcnt(10)" ::: "memory");
        __builtin_amdgcn_s_barrier();
        __builtin_amdgcn_sched_barrier(0);
    };

    bf16x8 bA[2][5], bB[2][5];

    STAGE(0, 0);
    LOADB(bA, 0);
    STAGE(1, 1);

    int sl = 0;
    for (int c = 0; c < CH; c += 2) {
        int rA = sl;
        int rB = rA + 1; if (rB == 3) rB = 0;
        int wA = rB + 1; if (wA == 3) wA = 0;
        int wB = rA;

        WAITBAR();
        LOADB(bB, c + 1);
        __builtin_amdgcn_sched_barrier(0x38F);
        if (c + 2 < CH) STAGE(c + 2, wA);
        COMPUTE(bA, rA);

        WAITBAR();
        if (c + 2 < CH) LOADB(bA, c + 2);
        __builtin_amdgcn_sched_barrier(0x38F);
        if (c + 3 < CH) STAGE(c + 3, wB);
        COMPUTE(bB, rB);

        sl = wA;
    }

    // epilogue: transposed store yt2[n][o][l]
    ushort_t* yp = yt + (size_t)n * (320 * 488);
#pragma unroll
    for (int ns = 0; ns < 5; ns++) {
        int o = wn + ns * 16 + lrow;
        if (o >= 300) continue;
        float bo = bias[o];
        ushort_t* orow = yp + (size_t)o * 488;
#pragma unroll
        for (int ms = 0; ms < 4; ms++) {
            int l = l0 + ms * 16 + quad * 4;
            if (l + 3 < Lout) {
                ushort4 v;
                v.x = f2b(tanhf(acc[ms][ns][0] + bo));
                v.y = f2b(tanhf(acc[ms][ns][1] + bo));
                v.z = f2b(tanhf(acc[ms][ns][2] + bo));
                v.w = f2b(tanhf(acc[ms][ns][3] + bo));
                *(ushort4*)&orow[l] = v;
            } else {
#pragma unroll
                for (int r = 0; r < 4; r++)
                    if (l + r < Lout) orow[l + r] = f2b(tanhf(acc[ms][ns][r] + bo));
            }
        }
    }
}

// ---------------------------------------------------------------------------
// 2-pass radix-select top-k on bf16 keys (k largest, ties -> smallest index).
// Used only for the g0 stage (contiguous reads & writes).
// ---------------------------------------------------------------------------
template <int EPT>
__global__ __launch_bounds__(256) void topk16_kernel(
    const ushort_t* __restrict__ src, int CC,
    long long s_n, long long s_c, long long s_e,
    int L, int k,
    ushort_t* __restrict__ out1, long long o1_off, long long o1_n,
    long long o1_c, long long o1_e,
    ushort_t* __restrict__ out2, long long o2_off, long long o2_n,
    long long o2_c, long long o2_e)
{
    __shared__ uint sbuf[257];
    __shared__ uint wtot[4];
    __shared__ uint bsel[2];
    __shared__ uint wsum[4];

    int row = blockIdx.x;
    int n = row / CC, c = row - n * CC;
    const ushort_t* sp = src + (size_t)n * s_n + (size_t)c * s_c;

    int tid = threadIdx.x, lane = tid & 63, wid = tid >> 6;
    int base = tid * EPT;

    uint key[EPT];
    if (EPT == 4 && s_e == 1) {
        ushort4 v = *(const ushort4*)&sp[base];
        key[0] = kmap16(v.x); key[1] = kmap16(v.y);
        key[2] = kmap16(v.z); key[3] = kmap16(v.w);
    } else {
#pragma unroll
        for (int e = 0; e < EPT; e++) {
            int i = base + e;
            key[e] = (i < L) ? kmap16(sp[(size_t)i * s_e]) : 0u;
        }
    }

    uint pmask = 0, pval = 0, rem = (uint)k;
#pragma unroll
    for (int shift = 8; shift >= 0; shift -= 8) {
        sbuf[tid] = 0;
        __syncthreads();
#pragma unroll
        for (int e = 0; e < EPT; e++) {
            int i = base + e;
            if (i < L && (key[e] & pmask) == pval)
                atomicAdd(&sbuf[(key[e] >> shift) & 255], 1u);
        }
        __syncthreads();
        uint sfx = sbuf[tid];
#pragma unroll
        for (int off = 1; off < 64; off <<= 1) {
            uint u2 = __shfl_down(sfx, off);
            if (lane + off < 64) sfx += u2;
        }
        if (lane == 0) wtot[wid] = sfx;
        __syncthreads();
        uint hi = 0;
        for (int w = wid + 1; w < 4; w++) hi += wtot[w];
        sbuf[tid] = sfx + hi;             // cnt_ge[bin=tid]
        if (tid == 0) sbuf[256] = 0;
        __syncthreads();
        uint cg = sbuf[tid], cgn = sbuf[tid + 1];
        if (cg >= rem && cgn < rem) { bsel[0] = (uint)tid; bsel[1] = rem - cgn; }
        __syncthreads();
        pval |= bsel[0] << shift;
        pmask |= 0xFFu << shift;
        rem = bsel[1];
        __syncthreads();
    }

    const uint T = pval;
    uint gtc = 0, eqc = 0;
#pragma unroll
    for (int e = 0; e < EPT; e++) {
        int i = base + e;
        if (i < L) {
            gtc += (key[e] > T) ? 1u : 0u;
            eqc += (key[e] == T) ? 1u : 0u;
        }
    }
    uint pack = (gtc << 16) | eqc;
    uint incl = pack;
#pragma unroll
    for (int off = 1; off < 64; off <<= 1) {
        uint u2 = __shfl_up(incl, off);
        if (lane >= off) incl += u2;
    }
    uint excl = incl - pack;
    if (lane == 63) wsum[wid] = incl;
    __syncthreads();
    uint badd = 0;
    for (int w = 0; w < wid; w++) badd += wsum[w];
    excl += badd;
    uint gt_before = excl >> 16, eq_before = excl & 0xffffu;

    ushort_t* dp1 = out1 + (size_t)o1_off + (size_t)n * o1_n + (size_t)c * o1_c;
    ushort_t* dp2 = out2 ? out2 + (size_t)o2_off + (size_t)n * o2_n + (size_t)c * o2_c
                         : (ushort_t*)0;
#pragma unroll
    for (int e = 0; e < EPT; e++) {
        int i = base + e;
        if (i >= L) break;
        uint kk = key[e];
        if (kk > T) {
            uint pos = gt_before + (eq_before < rem ? eq_before : rem);
            ushort_t v = kinv16(kk);
            dp1[(size_t)pos * o1_e] = v;
            if (dp2) dp2[(size_t)pos * o2_e] = v;
            gt_before++;
        } else if (kk == T) {
            if (eq_before < rem) {
                uint pos = gt_before + eq_before;
                ushort_t v = kinv16(kk);
                dp1[(size_t)pos * o1_e] = v;
                if (dp2) dp2[(size_t)pos * o2_e] = v;
            }
            eq_before++;
        }
    }
}

// ---------------------------------------------------------------------------
// Multi-column top-k for the p-stages.  Block = one n x 32 channels.
// Input: yt2[n][o][l] rows (contiguous).  32 columns staged in LDS; radix
// select with 8 threads/column (wave-synchronous, no block barriers inside);
// selected values staged in LDS tile [pos][32ch]; written out as full 64B
// lines to dgb16 row off+pos and (optionally) the conv-input pad buffer
// row 4+pos.  Invalid channels (>=300) produce zeros (match memset pads).
// ---------------------------------------------------------------------------
__global__ __launch_bounds__(256) void topk_cols_kernel(
    const ushort_t* __restrict__ yt2,
    int Lq, int Ld, int kq, int kd,
    ushort_t* __restrict__ qg, int qoff,
    ushort_t* __restrict__ dg, int doff,
    ushort_t* __restrict__ pq, long long pq_nstr,
    ushort_t* __restrict__ pd, long long pd_nstr)
{
    __shared__ __align__(16) ushort_t xin[32][488];   // 31232 B
    __shared__ __align__(16) uint hist[32 * 257];     // 32896 B, reused as otile
    ushort_t* otile = (ushort_t*)hist;                // [pos][32] halves

    int cg = blockIdx.x, n = blockIdx.y;
    int c0 = cg * 32;
    bool isq = (n < 16);
    int L = isq ? Lq : Ld;
    int k = isq ? kq : kd;
    int nd = isq ? n : n - 16;
    int tid = threadIdx.x;

    // ---- stage 32 channel rows (488 halves each) into LDS ----
    const ushort_t* src = yt2 + (size_t)n * (320 * 488) + (size_t)c0 * 488;
    for (int i = tid; i < 32 * 61; i += 256) {
        int j = i / 61, s = i - j * 61;
        *(uint4*)&xin[j][s * 8] = *(const uint4*)&src[(size_t)j * 488 + s * 8];
    }
    __syncthreads();

    int g = tid >> 3, r = tid & 7;        // column group, lane within group
    uint* hg = &hist[g * 257];
    bool cval = (c0 + g) < 300;
    int S = (L + 7) >> 3;
    int llo = r * S, lhi = llo + S;
    if (lhi > L) lhi = L;
    if (llo > L) llo = L;

    uint rem = (uint)k;
    uint bsel = 0;
    uint Tt = 0;

    // ---- two radix rounds (top byte, then low byte) ----
#pragma unroll
    for (int round = 0; round < 2; round++) {
        // clear own histogram (wave-synchronous within the 8-lane group)
        for (int t = r; t < 256; t += 8) hg[t] = 0;
        for (int l = llo; l < lhi; l++) {
            uint key = cval ? kmap16(xin[g][l]) : 0x8000u;
            if (round == 0)
                atomicAdd(&hg[key >> 8], 1u);
            else if ((key >> 8) == bsel)
                atomicAdd(&hg[key & 255u], 1u);
        }
        // scan: lane r owns bins [r*32, r*32+32)
        uint hv[32];
        uint Sr = 0;
        int b0 = r * 32;
#pragma unroll
        for (int t = 0; t < 32; t++) { hv[t] = hg[b0 + t]; Sr += hv[t]; }
        uint suf = Sr;
#pragma unroll
        for (int off = 1; off < 8; off <<= 1) {
            uint u = __shfl_down(suf, off);
            if (r + off < 8) suf += u;
        }
        uint acc = suf - Sr;              // count in bins above lane's range
        uint found = 0;
#pragma unroll
        for (int t = 31; t >= 0; t--) {
            uint h = hv[t];
            if (!found && acc < rem && acc + h >= rem)
                found = ((uint)(b0 + t) << 16) | (rem - acc);
            acc += h;
        }
#pragma unroll
        for (int off = 1; off < 8; off <<= 1) found |= __shfl_xor(found, off);
        if (round == 0) {
            bsel = found >> 16;
            rem = found & 0xffffu;
        } else {
            Tt = (bsel << 8) | (found >> 16);
            rem = found & 0xffffu;
        }
    }

    // ---- per-lane rank prefix (ascending l order across the 8 lanes) ----
    uint gtc = 0, eqc = 0;
    for (int l = llo; l < lhi; l++) {
        uint key = cval ? kmap16(xin[g][l]) : 0x8000u;
        gtc += (key > Tt) ? 1u : 0u;
        eqc += (key == Tt) ? 1u : 0u;
    }
    uint pack = (gtc << 16) | eqc, incl = pack;
#pragma unroll
    for (int off = 1; off < 8; off <<= 1) {
        uint u = __shfl_up(incl, off);
        if (r >= off) incl += u;
    }
    uint excl = incl - pack;
    uint gt_b = excl >> 16, eq_b = excl & 0xffffu;

    __syncthreads();                      // hist -> otile reuse

    for (int l = llo; l < lhi; l++) {
        uint key = cval ? kmap16(xin[g][l]) : 0x8000u;
        if (key > Tt) {
            uint pos = gt_b + (eq_b < rem ? eq_b : rem);
            otile[pos * 32 + g] = kinv16(key);
            gt_b++;
        } else if (key == Tt) {
            if (eq_b < rem) otile[(gt_b + eq_b) * 32 + g] = kinv16(key);
            eq_b++;
        }
    }
    __syncthreads();

    // ---- coalesced write-out: k rows x 64B per destination ----
    ushort_t* d1 = isq ? qg + ((size_t)nd * 480 + qoff) * 320 + c0
                       : dg + ((size_t)nd * 960 + doff) * 320 + c0;
    ushort_t* d2 = 0;
    if (isq) { if (pq) d2 = pq + (size_t)nd * pq_nstr + 4 * 320 + c0; }
    else     { if (pd) d2 = pd + (size_t)nd * pd_nstr + 4 * 320 + c0; }

    for (int i = tid; i < k * 8; i += 256) {
        int p = i >> 3, s = i & 7;
        ushort4 v = *(ushort4*)&otile[p * 32 + s * 4];
        *(ushort4*)&d1[(size_t)p * 320 + s * 4] = v;
        if (d2) *(ushort4*)&d2[(size_t)p * 320 + s * 4] = v;
    }
}

// ---------------------------------------------------------------------------
// qt GEMM: qtb[b,m,e] = bf16( sum_d qgb[b,m,d] * bwb[e,d] ).
// ---------------------------------------------------------------------------
__global__ __launch_bounds__(256) void qt_mfma_kernel(
    const ushort_t* __restrict__ qgb, const ushort_t* __restrict__ bwb,
    ushort_t* __restrict__ qtb)
{
    int mt = blockIdx.x, b = blockIdx.y;
    int tid = threadIdx.x, wid = tid >> 6, lane = tid & 63;
    int wn = wid * 80, lrow = lane & 15, quad = lane >> 4;

    const ushort_t* A = qgb + ((size_t)b * 480 + mt * 48 + lrow) * 320 + quad * 8;
    const ushort_t* B = bwb + (size_t)(wn + lrow) * 320 + quad * 8;

    floatx4 acc[3][5];
#pragma unroll
    for (int i = 0; i < 3; i++)
#pragma unroll
        for (int j = 0; j < 5; j++) acc[i][j] = (floatx4){0.f, 0.f, 0.f, 0.f};

#pragma unroll 5
    for (int c0 = 0; c0 < 320; c0 += 32) {
        bf16x8 af[3], bfr[5];
#pragma unroll
        for (int ms = 0; ms < 3; ms++)
            af[ms] = *(const bf16x8*)&A[(size_t)(ms * 16) * 320 + c0];
#pragma unroll
        for (int ns = 0; ns < 5; ns++)
            bfr[ns] = *(const bf16x8*)&B[(size_t)(ns * 16) * 320 + c0];
#pragma unroll
        for (int ms = 0; ms < 3; ms++)
#pragma unroll
            for (int ns = 0; ns < 5; ns++)
                acc[ms][ns] = __builtin_amdgcn_mfma_f32_16x16x32_bf16(
                    af[ms], bfr[ns], acc[ms][ns], 0, 0, 0);
    }

    ushort_t* out = qtb + ((size_t)b * 480 + mt * 48) * 320;
#pragma unroll
    for (int ms = 0; ms < 3; ms++)
#pragma unroll
        for (int ns = 0; ns < 5; ns++)
#pragma unroll
            for (int r = 0; r < 4; r++)
                out[(size_t)(ms * 16 + quad * 4 + r) * 320 + wn + ns * 16 + lrow] =
                    f2b(acc[ms][ns][r]);
}

// ---------------------------------------------------------------------------
// MFMA M-GEMM fused with pooling.
// ---------------------------------------------------------------------------
__global__ __launch_bounds__(256) void mpool_mfma_kernel(
    const ushort_t* __restrict__ qtb16, const ushort_t* __restrict__ dgb16,
    const float* __restrict__ bb, float* __restrict__ mp)
{
    __shared__ float pool[2 * 12 * 192];

    int jb = blockIdx.x;
    int qb = blockIdx.y;
    int n  = blockIdx.z;
    int b  = n & 15;

    int tid = threadIdx.x;
    int wid = tid >> 6, lane = tid & 63;
    int wm2 = wid >> 1;
    int wm = wm2 * 48, wn = (wid & 1) * 96;
    int lrow = lane & 15, quad = lane >> 4;

    const ushort_t* Abase = qtb16 + ((size_t)b * 480 + qb * 96 + wm) * 320 + quad * 8;
    const ushort_t* Bbase = dgb16 + ((size_t)n * 960 + jb * 192 + wn) * 320 + quad * 8;

    floatx4 acc[3][6];
#pragma unroll
    for (int i = 0; i < 3; i++)
#pragma unroll
        for (int j = 0; j < 6; j++) acc[i][j] = (floatx4){0.f, 0.f, 0.f, 0.f};

#pragma unroll 2
    for (int c0 = 0; c0 < 320; c0 += 32) {
        bf16x8 af[3], bfr[6];
#pragma unroll
        for (int mt = 0; mt < 3; mt++)
            af[mt] = *(const bf16x8*)&Abase[(size_t)(mt * 16 + lrow) * 320 + c0];
#pragma unroll
        for (int nt = 0; nt < 6; nt++)
            bfr[nt] = *(const bf16x8*)&Bbase[(size_t)(nt * 16 + lrow) * 320 + c0];
#pragma unroll
        for (int mt = 0; mt < 3; mt++)
#pragma unroll
            for (int nt = 0; nt < 6; nt++)
                acc[mt][nt] = __builtin_amdgcn_mfma_f32_16x16x32_bf16(
                    af[mt], bfr[nt], acc[mt][nt], 0, 0, 0);
    }

#pragma unroll
    for (int mt = 0; mt < 3; mt++) {
        int g = mt * 4 + quad;
#pragma unroll
        for (int nt = 0; nt < 6; nt++) {
            floatx4 a = acc[mt][nt];
            float rm = fmaxf(fmaxf(a[0], a[1]), fmaxf(a[2], a[3]));
            pool[(wm2 * 12 + g) * 192 + wn + nt * 16 + lrow] = rm;
        }
    }
    __syncthreads();

    if (tid < 64) {
        int qw = tid >> 3, jw = tid & 7;
        int slab = qw >> 2, w = qw & 3;
        float m = -INFINITY;
        const float* pp = &pool[(slab * 12 + w * 3) * 192 + jw * 24];
        for (int g = 0; g < 3; g++)
            for (int cc = 0; cc < 24; cc++)
                m = fmaxf(m, pp[g * 192 + cc]);
        float sig = 1.f / (1.f + expf(-(m + bb[0])));
        mp[(size_t)n * 1600 + (size_t)(qb * 8 + qw) * 40 + (jb * 8 + jw)] = sig;
    }
}

// ---------------------------------------------------------------------------
// Conv block, channel-parallel, atomicMax-merged (Y zeroed before launch).
// ---------------------------------------------------------------------------
#define OCG 10
__global__ __launch_bounds__(256) void convblock_atomic_kernel(
    const float* __restrict__ X, const float* __restrict__ w,
    const float* __restrict__ bias, uint* __restrict__ Y)
{
    __shared__ float xp[48 * 48];
    __shared__ float ys[47 * 47];
    __shared__ float t1[40 * 47];
    __shared__ float outacc[1600];

    int n = blockIdx.x, t = threadIdx.x;
    int oc0 = blockIdx.y * OCG;
    const float* xn = X + (size_t)n * 1600;
    for (int i = t; i < 48 * 48; i += 256) {
        int r = i / 48, c = i - r * 48;
        int rr = r - 4, cc = c - 4;
        xp[i] = (rr >= 0 && rr < 40 && cc >= 0 && cc < 40) ? xn[rr * 40 + cc] : 0.f;
    }
    for (int i = t; i < 1600; i += 256) outacc[i] = 0.f;
    __syncthreads();

    for (int oc = oc0; oc < oc0 + OCG; oc++) {
        float w00 = w[oc * 4 + 0], w01 = w[oc * 4 + 1];
        float w10 = w[oc * 4 + 2], w11 = w[oc * 4 + 3];
        float bo = bias[oc];
        for (int i = t; i < 47 * 47; i += 256) {
            int r = i / 47, c = i - r * 47;
            float v = xp[r * 48 + c] * w00 + xp[r * 48 + c + 1] * w01
                    + xp[(r + 1) * 48 + c] * w10 + xp[(r + 1) * 48 + c + 1] * w11 + bo;
            ys[i] = 1.f / (1.f + expf(-v));
        }
        __syncthreads();
        for (int i = t; i < 40 * 47; i += 256) {
            int r = i / 47, c = i - r * 47;
            int s = (47 * r) / 40, e = (47 * (r + 1) + 39) / 40;
            float m = ys[s * 47 + c];
            for (int x = s + 1; x < e; x++) m = fmaxf(m, ys[x * 47 + c]);
            t1[i] = m;
        }
        __syncthreads();
        for (int i = t; i < 1600; i += 256) {
            int r = i / 40, c = i - r * 40;
            int s = (47 * c) / 40, e = (47 * (c + 1) + 39) / 40;
            float m = t1[r * 47 + s];
            for (int x = s + 1; x < e; x++) m = fmaxf(m, t1[r * 47 + x]);
            outacc[i] = fmaxf(outacc[i], m);
        }
        __syncthreads();
    }
    for (int i = t; i < 1600; i += 256)
        atomicMax(&Y[(size_t)n * 1600 + i], __float_as_uint(outacc[i]));
}

// ---------------------------------------------------------------------------
// Head
// ---------------------------------------------------------------------------
__global__ __launch_bounds__(64) void head_kernel(
    const float* __restrict__ feat, const float* __restrict__ lw,
    const float* __restrict__ lb, float* __restrict__ out)
{
    __shared__ float hs[40];
    int n = blockIdx.x, t = threadIdx.x;
    const float* f = feat + (size_t)n * 1600;
    if (t < 40) {
        float a = 0.f;
        for (int j = 0; j < 40; j++) a += f[t * 40 + j] * lw[j];
        hs[t] = 1.f / (1.f + expf(-(a + lb[0])));
    }
    __syncthreads();
    if (t == 0) {
        float a = 0.f;
        for (int i = 0; i < 40; i++) a += hs[i] * lw[i];
        out[n] = 1.f / (1.f + expf(-(a + lb[0])));
    }
}

// ---------------------------------------------------------------------------
extern "C" void kernel_launch(void* const* d_in, const int* in_sizes, int n_in,
                              void* d_out, int out_size, void* d_ws, size_t ws_size,
                              hipStream_t stream) {
    const float* query    = (const float*)d_in[0];
    const float* pos_doc  = (const float*)d_in[1];
    const float* neg_docs = (const float*)d_in[2];
    const float* qw1 = (const float*)d_in[3];  const float* qb1 = (const float*)d_in[4];
    const float* qw2 = (const float*)d_in[5];  const float* qb2 = (const float*)d_in[6];
    const float* qw3 = (const float*)d_in[7];  const float* qb3 = (const float*)d_in[8];
    const float* dw1 = (const float*)d_in[9];  const float* db1 = (const float*)d_in[10];
    const float* dw2 = (const float*)d_in[11]; const float* db2 = (const float*)d_in[12];
    const float* dw3 = (const float*)d_in[13]; const float* db3 = (const float*)d_in[14];
    const float* bw  = (const float*)d_in[15]; const float* bb  = (const float*)d_in[16];
    const float* mw1 = (const float*)d_in[17]; const float* mb1 = (const float*)d_in[18];
    const float* mw2 = (const float*)d_in[19]; const float* mb2 = (const float*)d_in[20];
    const float* mw3 = (const float*)d_in[21]; const float* mb3 = (const float*)d_in[22];
    const float* lw  = (const float*)d_in[23]; const float* lb  = (const float*)d_in[24];

    float* ws = (float*)d_ws;
    // ---- layout (float offsets) ----
    ushort_t* qw1b  = (ushort_t*)(ws + 0);          // 320*2048 bf16
    ushort_t* qw2b  = (ushort_t*)(ws + 327680);     // 320*640
    ushort_t* qw3b  = (ushort_t*)(ws + 430080);
    ushort_t* dw1b  = (ushort_t*)(ws + 532480);
    ushort_t* dw2b  = (ushort_t*)(ws + 860160);
    ushort_t* dw3b  = (ushort_t*)(ws + 962560);
    ushort_t* bwb   = (ushort_t*)(ws + 1064960);    // 320*320
    ushort_t* qgb16 = (ushort_t*)(ws + 1116160);    // (16,480,320)
    ushort_t* dgb16 = (ushort_t*)(ws + 2344960);    // (80,960,320)
    ushort_t* yt    = (ushort_t*)(ws + 14632960);   // (96,320,488)  o-major
    ushort_t* qxb   = (ushort_t*)(ws + 22128640);   // (16,264,1024)
    ushort_t* p1q   = (ushort_t*)(ws + 22128640);   // (16,200,320)
    ushort_t* p2q   = (ushort_t*)(ws + 22640640);   // (16,104,320)
    ushort_t* dxb   = (ushort_t*)(ws + 24291328);   // (80,520,1024)
    ushort_t* p1d   = (ushort_t*)(ws + 24291328);   // (80,360,320)
    ushort_t* p2d   = (ushort_t*)(ws + 28899328);   // (80,200,320)
    ushort_t* qtb16 = (ushort_t*)(ws + 31459328);   // (16,480,320)
    float*    mp    = ws + 32688128;                // (80,40,40)
    float*    ya    = ws + 32816128;                // (80,40,40)
    float*    yb    = ws + 32944128;                // (80,40,40)
    float*    yc    = ws + 33072128;                // (80,40,40)

    // ---- weight prep (MFMA-fragment-packed layout) ----
    prep_w2_kernel<<<1280, 256, 0, stream>>>(qw1, qw1b, 1024, 1024);
    prep_w2_kernel<<<400, 256, 0, stream>>>(qw2, qw2b, 300, 320);
    prep_w2_kernel<<<400, 256, 0, stream>>>(qw3, qw3b, 300, 320);
    prep_w2_kernel<<<1280, 256, 0, stream>>>(dw1, dw1b, 1024, 1024);
    prep_w2_kernel<<<400, 256, 0, stream>>>(dw2, dw2b, 300, 320);
    prep_w2_kernel<<<400, 256, 0, stream>>>(dw3, dw3b, 300, 320);
    prep_bw_kernel<<<400, 256, 0, stream>>>(bw, bwb);

    // ---- input convert to padded bf16 ----
    {
        dim3 g(264, 16);
        x_pad_bf16_kernel<<<g, 256, 0, stream>>>(query, nullptr, 0,
                                                 239LL * 1024, 239, qxb, 264);
    }
    {
        dim3 g(520, 80);
        x_pad_bf16_kernel<<<g, 256, 0, stream>>>(pos_doc, neg_docs, 16,
                                                 479LL * 1024, 479, dxb, 520);
    }

    // ---- g0 top-ks (contiguous reads/writes, unchanged) ----
    topk16_kernel<4><<<16 * 239, 256, 0, stream>>>(
        qxb + 4 * 1024, 239, 264LL * 1024, 1024, 1, 1024, 300,
        qgb16, 0, 480LL * 320, 320, 1,
        nullptr, 0, 0, 0, 0);
    topk16_kernel<4><<<80 * 479, 256, 0, stream>>>(
        dxb + 4 * 1024, 479, 520LL * 1024, 1024, 1, 1024, 300,
        dgb16, 0, 960LL * 320, 320, 1,
        nullptr, 0, 0, 0, 0);

    // ---- conv1 (pipelined LDS conv, transposed output) ----
    {
        dim3 g(8, 96);
        conv_lds_kernel<1024><<<g, 256, 0, stream>>>(
            qxb, 264LL * 1024, dxb, 520LL * 1024,
            qw1b, dw1b, qb1, db1, 246, 486, 4, yt);
    }

    // ---- zero conv2/3 input pads ----
    hipMemsetAsync(p1q, 0, 16 * 200 * 320 * 2, stream);
    hipMemsetAsync(p2q, 0, 16 * 104 * 320 * 2, stream);
    hipMemsetAsync(p1d, 0, (size_t)80 * 360 * 320 * 2, stream);
    hipMemsetAsync(p2d, 0, (size_t)80 * 200 * 320 * 2, stream);
    // ---- zero conv-block outputs (atomicMax targets) ----
    hipMemsetAsync(ya, 0, 80 * 1600 * 4, stream);
    hipMemsetAsync(yb, 0, 80 * 1600 * 4, stream);
    hipMemsetAsync(yc, 0, 80 * 1600 * 4, stream);

    // ---- p1 top-ks (multi-column, line-coalesced) ----
    {
        dim3 g(10, 96);
        topk_cols_kernel<<<g, 256, 0, stream>>>(
            yt, 246, 486, 160, 320,
            qgb16, 239, dgb16, 479,
            p1q, 200LL * 320, p1d, 360LL * 320);
    }

    // ---- conv2 ----
    {
        dim3 g(6, 96);
        conv_lds_kernel<320><<<g, 256, 0, stream>>>(
            p1q, 200LL * 320, p1d, 360LL * 320,
            qw2b, dw2b, qb2, db2, 167, 327, 3, yt);
    }

    // ---- p2 top-ks ----
    {
        dim3 g(10, 96);
        topk_cols_kernel<<<g, 256, 0, stream>>>(
            yt, 167, 327, 80, 160,
            qgb16, 399, dgb16, 799,
            p2q, 104LL * 320, p2d, 200LL * 320);
    }

    // ---- conv3 ----
    {
        dim3 g(3, 96);
        conv_lds_kernel<320><<<g, 256, 0, stream>>>(
            p2q, 104LL * 320, p2d, 200LL * 320,
            qw3b, dw3b, qb3, db3, 87, 167, 2, yt);
    }

    // ---- p3 top-ks (k=1) ----
    {
        dim3 g(10, 96);
        topk_cols_kernel<<<g, 256, 0, stream>>>(
            yt, 87, 167, 1, 1,
            qgb16, 479, dgb16, 959,
            nullptr, 0, nullptr, 0);
    }

    // ---- qt GEMM + fused similarity/pool ----
    {
        dim3 g(10, 16);
        qt_mfma_kernel<<<g, 256, 0, stream>>>(qgb16, bwb, qtb16);
    }
    {
        dim3 g(5, 5, 80);
        mpool_mfma_kernel<<<g, 256, 0, stream>>>(qtb16, dgb16, bb, mp);
    }

    // ---- conv blocks (channel-parallel, atomicMax-merged) + head ----
    {
        dim3 g(80, 5);
        convblock_atomic_kernel<<<g, 256, 0, stream>>>(mp, mw1, mb1, (uint*)ya);
        convblock_atomic_kernel<<<g, 256, 0, stream>>>(ya, mw2, mb2, (uint*)yb);
        convblock_atomic_kernel<<<g, 256, 0, stream>>>(yb, mw3, mb3, (uint*)yc);
    }
    head_kernel<<<80, 64, 0, stream>>>(yc, lw, lb, (float*)d_out);
}

// Round 3
// 1100.583 us; speedup vs baseline: 1.1933x; 1.0284x over previous
//
#include <hip/hip_runtime.h>
#include <hip/hip_bf16.h>
#include <math.h>

typedef unsigned long long ull;
typedef unsigned int uint;
typedef unsigned short ushort_t;

typedef short bf16x8 __attribute__((ext_vector_type(8)));
typedef float floatx4 __attribute__((ext_vector_type(4)));

// ---------------------------------------------------------------------------
// fp32 -> bf16 (round-to-nearest-even-ish)
// ---------------------------------------------------------------------------
__device__ inline ushort_t f2b(float f) {
    uint u = __float_as_uint(f);
    u = u + 0x7fffu + ((u >> 16) & 1u);
    return (ushort_t)(u >> 16);
}

// order-preserving bf16(bits)->uint16 map and inverse
__device__ inline uint kmap16(ushort_t u) {
    return (u & 0x8000u) ? (uint)((~u) & 0xFFFFu) : (uint)(u | 0x8000u);
}
__device__ inline ushort_t kinv16(uint k) {
    return (k & 0x8000u) ? (ushort_t)(k ^ 0x8000u) : (ushort_t)((~k) & 0xFFFFu);
}

// async 16B global -> LDS (DMA).  LDS dest = wave-uniform base + lane*16.
__device__ inline void async_copy16(const void* g, void* l) {
    __builtin_amdgcn_global_load_lds(
        (const __attribute__((address_space(1))) void*)g,
        (__attribute__((address_space(3))) void*)l, 16, 0, 0);
}

// ---------------------------------------------------------------------------
// Prep: w (300, C, 2) fp32 -> MFMA-fragment-packed bf16:
// Wb[(((c*2+t)*20 + g)*512) + lane*8 + e] = w[o=g*16+(lane&15)][ch=c*32+(lane>>4)*8+e][t]
// ---------------------------------------------------------------------------
__global__ void prep_w2_kernel(const float* __restrict__ w, ushort_t* __restrict__ Wb,
                               int C, int CP) {
    int CHn = CP / 32;
    int total = CHn * 2 * 20 * 512;
    for (int i = blockIdx.x * blockDim.x + threadIdx.x; i < total;
         i += gridDim.x * blockDim.x) {
        int e = i & 7;
        int lane = (i >> 3) & 63;
        int rest = i >> 9;              // (c*2+t)*20 + g
        int g = rest % 20;
        int tc = rest / 20;
        int t = tc & 1, c = tc >> 1;
        int o = g * 16 + (lane & 15);
        int ch = c * 32 + (lane >> 4) * 8 + e;
        float v = (o < 300 && ch < C) ? w[((size_t)o * C + ch) * 2 + t] : 0.f;
        Wb[i] = f2b(v);
    }
}

// bw (300,300) fp32 -> bwb[e][d] bf16 (320x320, zero pad)
__global__ void prep_bw_kernel(const float* __restrict__ bw, ushort_t* __restrict__ bwb) {
    int i = blockIdx.x * 256 + threadIdx.x;
    if (i >= 320 * 320) return;
    int e = i / 320, d = i - e * 320;
    bwb[i] = (e < 300 && d < 300) ? f2b(bw[d * 300 + e]) : (ushort_t)0;
}

// ---------------------------------------------------------------------------
// Input fp32 -> padded bf16: dst[n][r][1024], value = src row r-4 (zero pad).
// ---------------------------------------------------------------------------
__global__ __launch_bounds__(256) void x_pad_bf16_kernel(
    const float* __restrict__ src, const float* __restrict__ src2, int split_n,
    long long s_nstr, int Lin, ushort_t* __restrict__ dst, int rows)
{
    int r = blockIdx.x, n = blockIdx.y;
    const float* sp = (split_n > 0 && n >= split_n)
                          ? src2 + (size_t)(n - split_n) * s_nstr
                          : src + (size_t)n * s_nstr;
    int g = r - 4;
    ushort_t* dp = dst + ((size_t)n * rows + r) * 1024;
    int c = threadIdx.x * 4;
    ushort4 o = {0, 0, 0, 0};
    if (g >= 0 && g < Lin) {
        float4 v = *(const float4*)&sp[(size_t)g * 1024 + c];
        o.x = f2b(v.x); o.y = f2b(v.y); o.z = f2b(v.z); o.w = f2b(v.w);
    }
    *(ushort4*)&dp[c] = o;
}

// ---------------------------------------------------------------------------
// Conv GEMM, pipelined (T2+T3+T4+T5).  Output TRANSPOSED: yt2[n][o=320][l=488]
// so that the downstream per-channel top-k reads a contiguous row.
// ---------------------------------------------------------------------------
template <int CP>
__global__ __launch_bounds__(256, 2) void conv_lds_kernel(
    const ushort_t* __restrict__ xq, long long xq_nstr,
    const ushort_t* __restrict__ xd, long long xd_nstr,
    const ushort_t* __restrict__ Wq, const ushort_t* __restrict__ Wd,
    const float* __restrict__ bq, const float* __restrict__ bd,
    int Lout_q, int Lout_d, int mtiles_q,
    ushort_t* __restrict__ yt)
{
    constexpr int CH = CP / 32;          // chunks (even: 32 or 10)
    constexpr int BUFB = 65 * 64;        // bytes per A buffer
    __shared__ ushort_t Abuf[3][65 * 32];

    int mt = blockIdx.x, n = blockIdx.y;
    bool isq = (n < 16);
    if (isq && mt >= mtiles_q) return;
    const ushort_t* x = isq ? xq + (size_t)n * xq_nstr
                            : xd + (size_t)(n - 16) * xd_nstr;
    const ushort_t* W = isq ? Wq : Wd;
    const float* bias = isq ? bq : bd;
    int Lout = isq ? Lout_q : Lout_d;
    int l0 = mt * 64;

    int tid = threadIdx.x, wid = tid >> 6, lane = tid & 63;
    int wn = wid * 80;
    int lrow = lane & 15, quad = lane >> 4;

    // staging: thread -> (row = tid/4, lds slot = tid%4); source slot is
    // XOR-swizzled so that LDS (row, s) holds global slot s ^ ((row>>1)&3).
    int srow = tid >> 2;
    int sslot = (tid & 3) ^ ((tid >> 3) & 3);
    const ushort_t* gMain = x + (size_t)(l0 + srow) * CP + sslot * 8;
    const ushort_t* gXtra = x + (size_t)(l0 + 64) * CP + wid * 8;

    // B: fragment-packed; per (c,t,ns) one contiguous 1KB block per wave.
    const ushort_t* Bw = W + ((size_t)wid * 5) * 512 + lane * 8;

    // A-fragment swizzled byte offsets (fixed per thread)
    int offA[2][4];
#pragma unroll
    for (int t = 0; t < 2; t++)
#pragma unroll
        for (int ms = 0; ms < 4; ms++) {
            int r = ms * 16 + lrow + t;
            offA[t][ms] = r * 64 + ((quad ^ ((r >> 1) & 3)) << 4);
        }

    floatx4 acc[4][5];
#pragma unroll
    for (int i = 0; i < 4; i++)
#pragma unroll
        for (int j = 0; j < 5; j++) acc[i][j] = (floatx4){0.f, 0.f, 0.f, 0.f};

    char* lds0 = (char*)&Abuf[0][0];

    auto STAGE = [&](int cc, int slot) {           // 2 vmem instrs per wave
        char* lb = lds0 + slot * BUFB;
        async_copy16(gMain + cc * 32, lb + wid * 1024);
        if (lane == 0) async_copy16(gXtra + cc * 32, lb + 4096 + wid * 16);
    };
    auto LOADB = [&](bf16x8 (&bf)[2][5], int cc) {  // 10 vmem instrs
#pragma unroll
        for (int t = 0; t < 2; t++)
#pragma unroll
            for (int ns = 0; ns < 5; ns++)
                bf[t][ns] = *(const bf16x8*)(Bw + (size_t)((cc * 2 + t) * 20 + ns) * 512);
    };
    auto COMPUTE = [&](bf16x8 (&bf)[2][5], int rslot) {
        const char* ab = lds0 + rslot * BUFB;
        __builtin_amdgcn_s_setprio(1);
#pragma unroll
        for (int t = 0; t < 2; t++) {
            bf16x8 af[4];
#pragma unroll
            for (int ms = 0; ms < 4; ms++)
                af[ms] = *(const bf16x8*)(ab + offA[t][ms]);
#pragma unroll
            for (int ms = 0; ms < 4; ms++)
#pragma unroll
                for (int ns = 0; ns < 5; ns++)
                    acc[ms][ns] = __builtin_amdgcn_mfma_f32_16x16x32_bf16(
                        af[ms], bf[t][ns], acc[ms][ns], 0, 0, 0);
        }
        __builtin_amdgcn_s_setprio(0);
    };
    auto WAITBAR = [&]() {
        asm volatile("s_waitcnt vmcnt(10)" ::: "memory");
        __builtin_amdgcn_s_barrier();
        __builtin_amdgcn_sched_barrier(0);
    };

    bf16x8 bA[2][5], bB[2][5];

    STAGE(0, 0);
    LOADB(bA, 0);
    STAGE(1, 1);

    int sl = 0;
    for (int c = 0; c < CH; c += 2) {
        int rA = sl;
        int rB = rA + 1; if (rB == 3) rB = 0;
        int wA = rB + 1; if (wA == 3) wA = 0;
        int wB = rA;

        WAITBAR();
        LOADB(bB, c + 1);
        __builtin_amdgcn_sched_barrier(0x38F);
        if (c + 2 < CH) STAGE(c + 2, wA);
        COMPUTE(bA, rA);

        WAITBAR();
        if (c + 2 < CH) LOADB(bA, c + 2);
        __builtin_amdgcn_sched_barrier(0x38F);
        if (c + 3 < CH) STAGE(c + 3, wB);
        COMPUTE(bB, rB);

        sl = wA;
    }

    // epilogue: transposed store yt2[n][o][l]
    ushort_t* yp = yt + (size_t)n * (320 * 488);
#pragma unroll
    for (int ns = 0; ns < 5; ns++) {
        int o = wn + ns * 16 + lrow;
        if (o >= 300) continue;
        float bo = bias[o];
        ushort_t* orow = yp + (size_t)o * 488;
#pragma unroll
        for (int ms = 0; ms < 4; ms++) {
            int l = l0 + ms * 16 + quad * 4;
            if (l + 3 < Lout) {
                ushort4 v;
                v.x = f2b(tanhf(acc[ms][ns][0] + bo));
                v.y = f2b(tanhf(acc[ms][ns][1] + bo));
                v.z = f2b(tanhf(acc[ms][ns][2] + bo));
                v.w = f2b(tanhf(acc[ms][ns][3] + bo));
                *(ushort4*)&orow[l] = v;
            } else {
#pragma unroll
                for (int r = 0; r < 4; r++)
                    if (l + r < Lout) orow[l + r] = f2b(tanhf(acc[ms][ns][r] + bo));
            }
        }
    }
}

// ---------------------------------------------------------------------------
// g0 top-k: wave-per-row radix select, k=300 of L=1024 contiguous bf16.
// One wave owns one row: 16 elements/lane, private 256-bin LDS histogram,
// all reductions wave-internal (shfl) -- zero block barriers.
// DS ops of a wave execute in order; sched_barrier(0) pins compiler order.
// Output: row of 300 values at out + n*o_n + c*o_c (ascending index order,
// ties -> smallest index; identical semantics to previous kernel).
// ---------------------------------------------------------------------------
__global__ __launch_bounds__(256) void topk_g0_kernel(
    const ushort_t* __restrict__ src, int CC, long long s_n,
    ushort_t* __restrict__ out, long long o_n, long long o_c)
{
    __shared__ uint hist[4][257];

    int tid = threadIdx.x, wid = tid >> 6, lane = tid & 63;
    int row = blockIdx.x * 4 + wid;
    int n = row / CC, c = row - n * CC;
    const ushort_t* sp = src + (size_t)n * s_n + (size_t)c * 1024;

    // ---- load 16 elements/lane (2 x 16B, wave reads 2KB contiguous) ----
    const uint* sp32 = (const uint*)(sp + (size_t)lane * 16);
    uint pk[8];
    {
        uint4 va = *(const uint4*)sp32;
        uint4 vb = *(const uint4*)(sp32 + 4);
        pk[0] = va.x; pk[1] = va.y; pk[2] = va.z; pk[3] = va.w;
        pk[4] = vb.x; pk[5] = vb.y; pk[6] = vb.z; pk[7] = vb.w;
    }
    uint key[16];
#pragma unroll
    for (int i = 0; i < 8; i++) {
        uint w = pk[i];
        uint s = w & 0x80008000u;
        w ^= 0x80008000u | ((s >> 15) * 0x7fffu);   // packed kmap16
        key[2 * i] = w & 0xffffu;
        key[2 * i + 1] = w >> 16;
    }

    uint* hg = hist[wid];
    uint rem = 300, bsel = 0, T = 0;

#pragma unroll
    for (int round = 0; round < 2; round++) {
        // clear own histogram
#pragma unroll
        for (int t = 0; t < 4; t++) hg[lane + t * 64] = 0;
        __builtin_amdgcn_sched_barrier(0);
        // accumulate
        if (round == 0) {
#pragma unroll
            for (int e = 0; e < 16; e++) atomicAdd(&hg[key[e] >> 8], 1u);
        } else {
#pragma unroll
            for (int e = 0; e < 16; e++)
                if ((key[e] >> 8) == bsel) atomicAdd(&hg[key[e] & 255u], 1u);
        }
        __builtin_amdgcn_sched_barrier(0);
        // descending scan: lane owns bins [4*lane, 4*lane+4)
        uint hv[4], Sr = 0;
#pragma unroll
        for (int t = 0; t < 4; t++) { hv[t] = hg[lane * 4 + t]; Sr += hv[t]; }
        uint suf = Sr;
#pragma unroll
        for (int off = 1; off < 64; off <<= 1) {
            uint u = __shfl_down(suf, off);
            if (lane + off < 64) suf += u;
        }
        uint acc = suf - Sr;              // count in bins above lane's range
        uint found = 0;
#pragma unroll
        for (int t = 3; t >= 0; t--) {
            uint h = hv[t];
            if (!found && acc < rem && acc + h >= rem)
                found = ((uint)(lane * 4 + t) << 16) | (rem - acc);
            acc += h;
        }
#pragma unroll
        for (int off = 1; off < 64; off <<= 1) found |= __shfl_xor(found, off);
        if (round == 0) {
            bsel = found >> 16;
            rem = found & 0xffffu;
        } else {
            T = (bsel << 8) | (found >> 16);
            rem = found & 0xffffu;
        }
        __builtin_amdgcn_sched_barrier(0);
    }

    // ---- rank prefix (elements lane*16+e ascending) ----
    uint gtc = 0, eqc = 0;
#pragma unroll
    for (int e = 0; e < 16; e++) {
        gtc += (key[e] > T) ? 1u : 0u;
        eqc += (key[e] == T) ? 1u : 0u;
    }
    uint pack = (gtc << 16) | eqc, incl = pack;
#pragma unroll
    for (int off = 1; off < 64; off <<= 1) {
        uint u = __shfl_up(incl, off);
        if (lane >= off) incl += u;
    }
    uint excl = incl - pack;
    uint gt_b = excl >> 16, eq_b = excl & 0xffffu;

    ushort_t* dp = out + (size_t)n * o_n + (size_t)c * o_c;
#pragma unroll
    for (int e = 0; e < 16; e++) {
        uint kk = key[e];
        if (kk > T) {
            uint pos = gt_b + (eq_b < rem ? eq_b : rem);
            dp[pos] = kinv16(kk);
            gt_b++;
        } else if (kk == T) {
            if (eq_b < rem) dp[gt_b + eq_b] = kinv16(kk);
            eq_b++;
        }
    }
}

// ---------------------------------------------------------------------------
// Multi-column top-k for the p-stages.  Block = one n x 32 channels.
// ---------------------------------------------------------------------------
__global__ __launch_bounds__(256) void topk_cols_kernel(
    const ushort_t* __restrict__ yt2,
    int Lq, int Ld, int kq, int kd,
    ushort_t* __restrict__ qg, int qoff,
    ushort_t* __restrict__ dg, int doff,
    ushort_t* __restrict__ pq, long long pq_nstr,
    ushort_t* __restrict__ pd, long long pd_nstr)
{
    __shared__ __align__(16) ushort_t xin[32][488];   // 31232 B
    __shared__ __align__(16) uint hist[32 * 257];     // 32896 B, reused as otile
    ushort_t* otile = (ushort_t*)hist;                // [pos][32] halves

    int cg = blockIdx.x, n = blockIdx.y;
    int c0 = cg * 32;
    bool isq = (n < 16);
    int L = isq ? Lq : Ld;
    int k = isq ? kq : kd;
    int nd = isq ? n : n - 16;
    int tid = threadIdx.x;

    // ---- stage 32 channel rows (488 halves each) into LDS ----
    const ushort_t* src = yt2 + (size_t)n * (320 * 488) + (size_t)c0 * 488;
    for (int i = tid; i < 32 * 61; i += 256) {
        int j = i / 61, s = i - j * 61;
        *(uint4*)&xin[j][s * 8] = *(const uint4*)&src[(size_t)j * 488 + s * 8];
    }
    __syncthreads();

    int g = tid >> 3, r = tid & 7;        // column group, lane within group
    uint* hg = &hist[g * 257];
    bool cval = (c0 + g) < 300;
    int S = (L + 7) >> 3;
    int llo = r * S, lhi = llo + S;
    if (lhi > L) lhi = L;
    if (llo > L) llo = L;

    uint rem = (uint)k;
    uint bsel = 0;
    uint Tt = 0;

    // ---- two radix rounds (top byte, then low byte) ----
#pragma unroll
    for (int round = 0; round < 2; round++) {
        for (int t = r; t < 256; t += 8) hg[t] = 0;
        for (int l = llo; l < lhi; l++) {
            uint key = cval ? kmap16(xin[g][l]) : 0x8000u;
            if (round == 0)
                atomicAdd(&hg[key >> 8], 1u);
            else if ((key >> 8) == bsel)
                atomicAdd(&hg[key & 255u], 1u);
        }
        uint hv[32];
        uint Sr = 0;
        int b0 = r * 32;
#pragma unroll
        for (int t = 0; t < 32; t++) { hv[t] = hg[b0 + t]; Sr += hv[t]; }
        uint suf = Sr;
#pragma unroll
        for (int off = 1; off < 8; off <<= 1) {
            uint u = __shfl_down(suf, off);
            if (r + off < 8) suf += u;
        }
        uint acc = suf - Sr;
        uint found = 0;
#pragma unroll
        for (int t = 31; t >= 0; t--) {
            uint h = hv[t];
            if (!found && acc < rem && acc + h >= rem)
                found = ((uint)(b0 + t) << 16) | (rem - acc);
            acc += h;
        }
#pragma unroll
        for (int off = 1; off < 8; off <<= 1) found |= __shfl_xor(found, off);
        if (round == 0) {
            bsel = found >> 16;
            rem = found & 0xffffu;
        } else {
            Tt = (bsel << 8) | (found >> 16);
            rem = found & 0xffffu;
        }
    }

    // ---- per-lane rank prefix (ascending l order across the 8 lanes) ----
    uint gtc = 0, eqc = 0;
    for (int l = llo; l < lhi; l++) {
        uint key = cval ? kmap16(xin[g][l]) : 0x8000u;
        gtc += (key > Tt) ? 1u : 0u;
        eqc += (key == Tt) ? 1u : 0u;
    }
    uint pack = (gtc << 16) | eqc, incl = pack;
#pragma unroll
    for (int off = 1; off < 8; off <<= 1) {
        uint u = __shfl_up(incl, off);
        if (r >= off) incl += u;
    }
    uint excl = incl - pack;
    uint gt_b = excl >> 16, eq_b = excl & 0xffffu;

    __syncthreads();                      // hist -> otile reuse

    for (int l = llo; l < lhi; l++) {
        uint key = cval ? kmap16(xin[g][l]) : 0x8000u;
        if (key > Tt) {
            uint pos = gt_b + (eq_b < rem ? eq_b : rem);
            otile[pos * 32 + g] = kinv16(key);
            gt_b++;
        } else if (key == Tt) {
            if (eq_b < rem) otile[(gt_b + eq_b) * 32 + g] = kinv16(key);
            eq_b++;
        }
    }
    __syncthreads();

    // ---- coalesced write-out: k rows x 64B per destination ----
    ushort_t* d1 = isq ? qg + ((size_t)nd * 480 + qoff) * 320 + c0
                       : dg + ((size_t)nd * 960 + doff) * 320 + c0;
    ushort_t* d2 = 0;
    if (isq) { if (pq) d2 = pq + (size_t)nd * pq_nstr + 4 * 320 + c0; }
    else     { if (pd) d2 = pd + (size_t)nd * pd_nstr + 4 * 320 + c0; }

    for (int i = tid; i < k * 8; i += 256) {
        int p = i >> 3, s = i & 7;
        ushort4 v = *(ushort4*)&otile[p * 32 + s * 4];
        *(ushort4*)&d1[(size_t)p * 320 + s * 4] = v;
        if (d2) *(ushort4*)&d2[(size_t)p * 320 + s * 4] = v;
    }
}

// ---------------------------------------------------------------------------
// qt GEMM: qtb[b,m,e] = bf16( sum_d qgb[b,m,d] * bwb[e,d] ).
// ---------------------------------------------------------------------------
__global__ __launch_bounds__(256) void qt_mfma_kernel(
    const ushort_t* __restrict__ qgb, const ushort_t* __restrict__ bwb,
    ushort_t* __restrict__ qtb)
{
    int mt = blockIdx.x, b = blockIdx.y;
    int tid = threadIdx.x, wid = tid >> 6, lane = tid & 63;
    int wn = wid * 80, lrow = lane & 15, quad = lane >> 4;

    const ushort_t* A = qgb + ((size_t)b * 480 + mt * 48 + lrow) * 320 + quad * 8;
    const ushort_t* B = bwb + (size_t)(wn + lrow) * 320 + quad * 8;

    floatx4 acc[3][5];
#pragma unroll
    for (int i = 0; i < 3; i++)
#pragma unroll
        for (int j = 0; j < 5; j++) acc[i][j] = (floatx4){0.f, 0.f, 0.f, 0.f};

#pragma unroll 5
    for (int c0 = 0; c0 < 320; c0 += 32) {
        bf16x8 af[3], bfr[5];
#pragma unroll
        for (int ms = 0; ms < 3; ms++)
            af[ms] = *(const bf16x8*)&A[(size_t)(ms * 16) * 320 + c0];
#pragma unroll
        for (int ns = 0; ns < 5; ns++)
            bfr[ns] = *(const bf16x8*)&B[(size_t)(ns * 16) * 320 + c0];
#pragma unroll
        for (int ms = 0; ms < 3; ms++)
#pragma unroll
            for (int ns = 0; ns < 5; ns++)
                acc[ms][ns] = __builtin_amdgcn_mfma_f32_16x16x32_bf16(
                    af[ms], bfr[ns], acc[ms][ns], 0, 0, 0);
    }

    ushort_t* out = qtb + ((size_t)b * 480 + mt * 48) * 320;
#pragma unroll
    for (int ms = 0; ms < 3; ms++)
#pragma unroll
        for (int ns = 0; ns < 5; ns++)
#pragma unroll
            for (int r = 0; r < 4; r++)
                out[(size_t)(ms * 16 + quad * 4 + r) * 320 + wn + ns * 16 + lrow] =
                    f2b(acc[ms][ns][r]);
}

// ---------------------------------------------------------------------------
// MFMA M-GEMM fused with pooling.
// ---------------------------------------------------------------------------
__global__ __launch_bounds__(256) void mpool_mfma_kernel(
    const ushort_t* __restrict__ qtb16, const ushort_t* __restrict__ dgb16,
    const float* __restrict__ bb, float* __restrict__ mp)
{
    __shared__ float pool[2 * 12 * 192];

    int jb = blockIdx.x;
    int qb = blockIdx.y;
    int n  = blockIdx.z;
    int b  = n & 15;

    int tid = threadIdx.x;
    int wid = tid >> 6, lane = tid & 63;
    int wm2 = wid >> 1;
    int wm = wm2 * 48, wn = (wid & 1) * 96;
    int lrow = lane & 15, quad = lane >> 4;

    const ushort_t* Abase = qtb16 + ((size_t)b * 480 + qb * 96 + wm) * 320 + quad * 8;
    const ushort_t* Bbase = dgb16 + ((size_t)n * 960 + jb * 192 + wn) * 320 + quad * 8;

    floatx4 acc[3][6];
#pragma unroll
    for (int i = 0; i < 3; i++)
#pragma unroll
        for (int j = 0; j < 6; j++) acc[i][j] = (floatx4){0.f, 0.f, 0.f, 0.f};

#pragma unroll 2
    for (int c0 = 0; c0 < 320; c0 += 32) {
        bf16x8 af[3], bfr[6];
#pragma unroll
        for (int mt = 0; mt < 3; mt++)
            af[mt] = *(const bf16x8*)&Abase[(size_t)(mt * 16 + lrow) * 320 + c0];
#pragma unroll
        for (int nt = 0; nt < 6; nt++)
            bfr[nt] = *(const bf16x8*)&Bbase[(size_t)(nt * 16 + lrow) * 320 + c0];
#pragma unroll
        for (int mt = 0; mt < 3; mt++)
#pragma unroll
            for (int nt = 0; nt < 6; nt++)
                acc[mt][nt] = __builtin_amdgcn_mfma_f32_16x16x32_bf16(
                    af[mt], bfr[nt], acc[mt][nt], 0, 0, 0);
    }

#pragma unroll
    for (int mt = 0; mt < 3; mt++) {
        int g = mt * 4 + quad;
#pragma unroll
        for (int nt = 0; nt < 6; nt++) {
            floatx4 a = acc[mt][nt];
            float rm = fmaxf(fmaxf(a[0], a[1]), fmaxf(a[2], a[3]));
            pool[(wm2 * 12 + g) * 192 + wn + nt * 16 + lrow] = rm;
        }
    }
    __syncthreads();

    if (tid < 64) {
        int qw = tid >> 3, jw = tid & 7;
        int slab = qw >> 2, w = qw & 3;
        float m = -INFINITY;
        const float* pp = &pool[(slab * 12 + w * 3) * 192 + jw * 24];
        for (int g = 0; g < 3; g++)
            for (int cc = 0; cc < 24; cc++)
                m = fmaxf(m, pp[g * 192 + cc]);
        float sig = 1.f / (1.f + expf(-(m + bb[0])));
        mp[(size_t)n * 1600 + (size_t)(qb * 8 + qw) * 40 + (jb * 8 + jw)] = sig;
    }
}

// ---------------------------------------------------------------------------
// Conv block, channel-parallel, atomicMax-merged (Y zeroed before launch).
// ---------------------------------------------------------------------------
#define OCG 10
__global__ __launch_bounds__(256) void convblock_atomic_kernel(
    const float* __restrict__ X, const float* __restrict__ w,
    const float* __restrict__ bias, uint* __restrict__ Y)
{
    __shared__ float xp[48 * 48];
    __shared__ float ys[47 * 47];
    __shared__ float t1[40 * 47];
    __shared__ float outacc[1600];

    int n = blockIdx.x, t = threadIdx.x;
    int oc0 = blockIdx.y * OCG;
    const float* xn = X + (size_t)n * 1600;
    for (int i = t; i < 48 * 48; i += 256) {
        int r = i / 48, c = i - r * 48;
        int rr = r - 4, cc = c - 4;
        xp[i] = (rr >= 0 && rr < 40 && cc >= 0 && cc < 40) ? xn[rr * 40 + cc] : 0.f;
    }
    for (int i = t; i < 1600; i += 256) outacc[i] = 0.f;
    __syncthreads();

    for (int oc = oc0; oc < oc0 + OCG; oc++) {
        float w00 = w[oc * 4 + 0], w01 = w[oc * 4 + 1];
        float w10 = w[oc * 4 + 2], w11 = w[oc * 4 + 3];
        float bo = bias[oc];
        for (int i = t; i < 47 * 47; i += 256) {
            int r = i / 47, c = i - r * 47;
            float v = xp[r * 48 + c] * w00 + xp[r * 48 + c + 1] * w01
                    + xp[(r + 1) * 48 + c] * w10 + xp[(r + 1) * 48 + c + 1] * w11 + bo;
            ys[i] = 1.f / (1.f + expf(-v));
        }
        __syncthreads();
        for (int i = t; i < 40 * 47; i += 256) {
            int r = i / 47, c = i - r * 47;
            int s = (47 * r) / 40, e = (47 * (r + 1) + 39) / 40;
            float m = ys[s * 47 + c];
            for (int x = s + 1; x < e; x++) m = fmaxf(m, ys[x * 47 + c]);
            t1[i] = m;
        }
        __syncthreads();
        for (int i = t; i < 1600; i += 256) {
            int r = i / 40, c = i - r * 40;
            int s = (47 * c) / 40, e = (47 * (c + 1) + 39) / 40;
            float m = t1[r * 47 + s];
            for (int x = s + 1; x < e; x++) m = fmaxf(m, t1[r * 47 + x]);
            outacc[i] = fmaxf(outacc[i], m);
        }
        __syncthreads();
    }
    for (int i = t; i < 1600; i += 256)
        atomicMax(&Y[(size_t)n * 1600 + i], __float_as_uint(outacc[i]));
}

// ---------------------------------------------------------------------------
// Head
// ---------------------------------------------------------------------------
__global__ __launch_bounds__(64) void head_kernel(
    const float* __restrict__ feat, const float* __restrict__ lw,
    const float* __restrict__ lb, float* __restrict__ out)
{
    __shared__ float hs[40];
    int n = blockIdx.x, t = threadIdx.x;
    const float* f = feat + (size_t)n * 1600;
    if (t < 40) {
        float a = 0.f;
        for (int j = 0; j < 40; j++) a += f[t * 40 + j] * lw[j];
        hs[t] = 1.f / (1.f + expf(-(a + lb[0])));
    }
    __syncthreads();
    if (t == 0) {
        float a = 0.f;
        for (int i = 0; i < 40; i++) a += hs[i] * lw[i];
        out[n] = 1.f / (1.f + expf(-(a + lb[0])));
    }
}

// ---------------------------------------------------------------------------
extern "C" void kernel_launch(void* const* d_in, const int* in_sizes, int n_in,
                              void* d_out, int out_size, void* d_ws, size_t ws_size,
                              hipStream_t stream) {
    const float* query    = (const float*)d_in[0];
    const float* pos_doc  = (const float*)d_in[1];
    const float* neg_docs = (const float*)d_in[2];
    const float* qw1 = (const float*)d_in[3];  const float* qb1 = (const float*)d_in[4];
    const float* qw2 = (const float*)d_in[5];  const float* qb2 = (const float*)d_in[6];
    const float* qw3 = (const float*)d_in[7];  const float* qb3 = (const float*)d_in[8];
    const float* dw1 = (const float*)d_in[9];  const float* db1 = (const float*)d_in[10];
    const float* dw2 = (const float*)d_in[11]; const float* db2 = (const float*)d_in[12];
    const float* dw3 = (const float*)d_in[13]; const float* db3 = (const float*)d_in[14];
    const float* bw  = (const float*)d_in[15]; const float* bb  = (const float*)d_in[16];
    const float* mw1 = (const float*)d_in[17]; const float* mb1 = (const float*)d_in[18];
    const float* mw2 = (const float*)d_in[19]; const float* mb2 = (const float*)d_in[20];
    const float* mw3 = (const float*)d_in[21]; const float* mb3 = (const float*)d_in[22];
    const float* lw  = (const float*)d_in[23]; const float* lb  = (const float*)d_in[24];

    float* ws = (float*)d_ws;
    // ---- layout (float offsets) ----
    ushort_t* qw1b  = (ushort_t*)(ws + 0);          // 320*2048 bf16
    ushort_t* qw2b  = (ushort_t*)(ws + 327680);     // 320*640
    ushort_t* qw3b  = (ushort_t*)(ws + 430080);
    ushort_t* dw1b  = (ushort_t*)(ws + 532480);
    ushort_t* dw2b  = (ushort_t*)(ws + 860160);
    ushort_t* dw3b  = (ushort_t*)(ws + 962560);
    ushort_t* bwb   = (ushort_t*)(ws + 1064960);    // 320*320
    ushort_t* qgb16 = (ushort_t*)(ws + 1116160);    // (16,480,320)
    ushort_t* dgb16 = (ushort_t*)(ws + 2344960);    // (80,960,320)
    ushort_t* yt    = (ushort_t*)(ws + 14632960);   // (96,320,488)  o-major
    ushort_t* qxb   = (ushort_t*)(ws + 22128640);   // (16,264,1024)
    ushort_t* p1q   = (ushort_t*)(ws + 22128640);   // (16,200,320)
    ushort_t* p2q   = (ushort_t*)(ws + 22640640);   // (16,104,320)
    ushort_t* dxb   = (ushort_t*)(ws + 24291328);   // (80,520,1024)
    ushort_t* p1d   = (ushort_t*)(ws + 24291328);   // (80,360,320)
    ushort_t* p2d   = (ushort_t*)(ws + 28899328);   // (80,200,320)
    ushort_t* qtb16 = (ushort_t*)(ws + 31459328);   // (16,480,320)
    float*    mp    = ws + 32688128;                // (80,40,40)
    float*    ya    = ws + 32816128;                // (80,40,40)
    float*    yb    = ws + 32944128;                // (80,40,40)
    float*    yc    = ws + 33072128;                // (80,40,40)

    // ---- weight prep (MFMA-fragment-packed layout) ----
    prep_w2_kernel<<<1280, 256, 0, stream>>>(qw1, qw1b, 1024, 1024);
    prep_w2_kernel<<<400, 256, 0, stream>>>(qw2, qw2b, 300, 320);
    prep_w2_kernel<<<400, 256, 0, stream>>>(qw3, qw3b, 300, 320);
    prep_w2_kernel<<<1280, 256, 0, stream>>>(dw1, dw1b, 1024, 1024);
    prep_w2_kernel<<<400, 256, 0, stream>>>(dw2, dw2b, 300, 320);
    prep_w2_kernel<<<400, 256, 0, stream>>>(dw3, dw3b, 300, 320);
    prep_bw_kernel<<<400, 256, 0, stream>>>(bw, bwb);

    // ---- input convert to padded bf16 ----
    {
        dim3 g(264, 16);
        x_pad_bf16_kernel<<<g, 256, 0, stream>>>(query, nullptr, 0,
                                                 239LL * 1024, 239, qxb, 264);
    }
    {
        dim3 g(520, 80);
        x_pad_bf16_kernel<<<g, 256, 0, stream>>>(pos_doc, neg_docs, 16,
                                                 479LL * 1024, 479, dxb, 520);
    }

    // ---- g0 top-ks (wave-per-row radix select) ----
    topk_g0_kernel<<<(16 * 239) / 4, 256, 0, stream>>>(
        qxb + 4 * 1024, 239, 264LL * 1024, qgb16, 480LL * 320, 320);
    topk_g0_kernel<<<(80 * 479) / 4, 256, 0, stream>>>(
        dxb + 4 * 1024, 479, 520LL * 1024, dgb16, 960LL * 320, 320);

    // ---- conv1 (pipelined LDS conv, transposed output) ----
    {
        dim3 g(8, 96);
        conv_lds_kernel<1024><<<g, 256, 0, stream>>>(
            qxb, 264LL * 1024, dxb, 520LL * 1024,
            qw1b, dw1b, qb1, db1, 246, 486, 4, yt);
    }

    // ---- zero conv2/3 input pads ----
    hipMemsetAsync(p1q, 0, 16 * 200 * 320 * 2, stream);
    hipMemsetAsync(p2q, 0, 16 * 104 * 320 * 2, stream);
    hipMemsetAsync(p1d, 0, (size_t)80 * 360 * 320 * 2, stream);
    hipMemsetAsync(p2d, 0, (size_t)80 * 200 * 320 * 2, stream);
    // ---- zero conv-block outputs (atomicMax targets) ----
    hipMemsetAsync(ya, 0, 80 * 1600 * 4, stream);
    hipMemsetAsync(yb, 0, 80 * 1600 * 4, stream);
    hipMemsetAsync(yc, 0, 80 * 1600 * 4, stream);

    // ---- p1 top-ks (multi-column, line-coalesced) ----
    {
        dim3 g(10, 96);
        topk_cols_kernel<<<g, 256, 0, stream>>>(
            yt, 246, 486, 160, 320,
            qgb16, 239, dgb16, 479,
            p1q, 200LL * 320, p1d, 360LL * 320);
    }

    // ---- conv2 ----
    {
        dim3 g(6, 96);
        conv_lds_kernel<320><<<g, 256, 0, stream>>>(
            p1q, 200LL * 320, p1d, 360LL * 320,
            qw2b, dw2b, qb2, db2, 167, 327, 3, yt);
    }

    // ---- p2 top-ks ----
    {
        dim3 g(10, 96);
        topk_cols_kernel<<<g, 256, 0, stream>>>(
            yt, 167, 327, 80, 160,
            qgb16, 399, dgb16, 799,
            p2q, 104LL * 320, p2d, 200LL * 320);
    }

    // ---- conv3 ----
    {
        dim3 g(3, 96);
        conv_lds_kernel<320><<<g, 256, 0, stream>>>(
            p2q, 104LL * 320, p2d, 200LL * 320,
            qw3b, dw3b, qb3, db3, 87, 167, 2, yt);
    }

    // ---- p3 top-ks (k=1) ----
    {
        dim3 g(10, 96);
        topk_cols_kernel<<<g, 256, 0, stream>>>(
            yt, 87, 167, 1, 1,
            qgb16, 479, dgb16, 959,
            nullptr, 0, nullptr, 0);
    }

    // ---- qt GEMM + fused similarity/pool ----
    {
        dim3 g(10, 16);
        qt_mfma_kernel<<<g, 256, 0, stream>>>(qgb16, bwb, qtb16);
    }
    {
        dim3 g(5, 5, 80);
        mpool_mfma_kernel<<<g, 256, 0, stream>>>(qtb16, dgb16, bb, mp);
    }

    // ---- conv blocks (channel-parallel, atomicMax-merged) + head ----
    {
        dim3 g(80, 5);
        convblock_atomic_kernel<<<g, 256, 0, stream>>>(mp, mw1, mb1, (uint*)ya);
        convblock_atomic_kernel<<<g, 256, 0, stream>>>(ya, mw2, mb2, (uint*)yb);
        convblock_atomic_kernel<<<g, 256, 0, stream>>>(yb, mw3, mb3, (uint*)yc);
    }
    head_kernel<<<80, 64, 0, stream>>>(yc, lw, lb, (float*)d_out);
}

// Round 5
// 1074.263 us; speedup vs baseline: 1.2225x; 1.0245x over previous
//
#include <hip/hip_runtime.h>
#include <hip/hip_bf16.h>
#include <math.h>

typedef unsigned long long ull;
typedef unsigned int uint;
typedef unsigned short ushort_t;

typedef short bf16x8 __attribute__((ext_vector_type(8)));
typedef float floatx4 __attribute__((ext_vector_type(4)));

// ---------------------------------------------------------------------------
// fp32 -> bf16 (round-to-nearest-even-ish)
// ---------------------------------------------------------------------------
__device__ inline ushort_t f2b(float f) {
    uint u = __float_as_uint(f);
    u = u + 0x7fffu + ((u >> 16) & 1u);
    return (ushort_t)(u >> 16);
}

// order-preserving bf16(bits)->uint16 map and inverse
__device__ inline uint kmap16(ushort_t u) {
    return (u & 0x8000u) ? (uint)((~u) & 0xFFFFu) : (uint)(u | 0x8000u);
}
__device__ inline ushort_t kinv16(uint k) {
    return (k & 0x8000u) ? (ushort_t)(k ^ 0x8000u) : (ushort_t)((~k) & 0xFFFFu);
}

// async 16B global -> LDS (DMA).  LDS dest = wave-uniform base + lane*16.
__device__ inline void async_copy16(const void* g, void* l) {
    __builtin_amdgcn_global_load_lds(
        (const __attribute__((address_space(1))) void*)g,
        (__attribute__((address_space(3))) void*)l, 16, 0, 0);
}

// ---------------------------------------------------------------------------
// Prep: w (300, C, 2) fp32 -> MFMA-fragment-packed bf16:
// Wb[(((c*2+t)*20 + g)*512) + lane*8 + e] = w[o=g*16+(lane&15)][ch=c*32+(lane>>4)*8+e][t]
// ---------------------------------------------------------------------------
__global__ void prep_w2_kernel(const float* __restrict__ w, ushort_t* __restrict__ Wb,
                               int C, int CP) {
    int CHn = CP / 32;
    int total = CHn * 2 * 20 * 512;
    for (int i = blockIdx.x * blockDim.x + threadIdx.x; i < total;
         i += gridDim.x * blockDim.x) {
        int e = i & 7;
        int lane = (i >> 3) & 63;
        int rest = i >> 9;              // (c*2+t)*20 + g
        int g = rest % 20;
        int tc = rest / 20;
        int t = tc & 1, c = tc >> 1;
        int o = g * 16 + (lane & 15);
        int ch = c * 32 + (lane >> 4) * 8 + e;
        float v = (o < 300 && ch < C) ? w[((size_t)o * C + ch) * 2 + t] : 0.f;
        Wb[i] = f2b(v);
    }
}

// bw (300,300) fp32 -> bwb[e][d] bf16 (320x320, zero pad)
__global__ void prep_bw_kernel(const float* __restrict__ bw, ushort_t* __restrict__ bwb) {
    int i = blockIdx.x * 256 + threadIdx.x;
    if (i >= 320 * 320) return;
    int e = i / 320, d = i - e * 320;
    bwb[i] = (e < 300 && d < 300) ? f2b(bw[d * 300 + e]) : (ushort_t)0;
}

// ---------------------------------------------------------------------------
// Input fp32 -> padded bf16: dst[n][r][1024], value = src row r-4 (zero pad).
// ---------------------------------------------------------------------------
__global__ __launch_bounds__(256) void x_pad_bf16_kernel(
    const float* __restrict__ src, const float* __restrict__ src2, int split_n,
    long long s_nstr, int Lin, ushort_t* __restrict__ dst, int rows)
{
    int r = blockIdx.x, n = blockIdx.y;
    const float* sp = (split_n > 0 && n >= split_n)
                          ? src2 + (size_t)(n - split_n) * s_nstr
                          : src + (size_t)n * s_nstr;
    int g = r - 4;
    ushort_t* dp = dst + ((size_t)n * rows + r) * 1024;
    int c = threadIdx.x * 4;
    ushort4 o = {0, 0, 0, 0};
    if (g >= 0 && g < Lin) {
        float4 v = *(const float4*)&sp[(size_t)g * 1024 + c];
        o.x = f2b(v.x); o.y = f2b(v.y); o.z = f2b(v.z); o.w = f2b(v.w);
    }
    *(ushort4*)&dp[c] = o;
}

// ---------------------------------------------------------------------------
// Conv GEMM, barrier-free wave-independent pipeline.
// Each WAVE = one unit (mt, nt, n): 64 M-rows x 64 N-cols, K=2*CP.
// A: wave-PRIVATE 3-slot LDS pipeline (prefetch depth 2), staged with 5
//    global_load_lds per chunk (4 full-wave 1KB + 1 four-lane 64B for the
//    tap-overlap row), XOR-swizzled via pre-swizzled global source.
// Self-sync: counted s_waitcnt vmcnt (no s_barrier anywhere).
//   FIFO accounting per wave/chunk: LOADB(8) + STAGE(5).  At chunk-c top,
//   ops newer than DMA(c): B_{c-1}(8, mostly drained) + DMA(c+1)(5);
//   vmcnt(8) retires DMA(c) in steady state AND exactly in the tail
//   (STAGE skipped).  c=0: outstanding = DMA(0)(5)+DMA(1)(5) -> vmcnt(5).
// B: fragment-packed (1KB coalesced per load), single-buffered registers;
//    L2-hit latency hidden by 3 waves/SIMD TLP.
// Units ordered nt-fastest so the 5 readers of one A panel co-reside on a
// CU (A re-reads hit L1/L2).
// Output TRANSPOSED: yt2[n][o=320][l=488].
// ---------------------------------------------------------------------------
template <int CP>
__global__ __launch_bounds__(256, 3) void conv_wave_kernel(
    const ushort_t* __restrict__ xq, long long xq_nstr,
    const ushort_t* __restrict__ xd, long long xd_nstr,
    const ushort_t* __restrict__ Wq, const ushort_t* __restrict__ Wd,
    const float* __restrict__ bq, const float* __restrict__ bd,
    int Lout_q, int Lout_d, int mtiles_q, int mtiles_d,
    ushort_t* __restrict__ yt)
{
    constexpr int CH = CP / 32;            // chunks
    __shared__ char Abuf[4][3][4160];      // [wave][slot][65 rows * 64 B]

    int tid = threadIdx.x, wid = tid >> 6, lane = tid & 63;
    int u = blockIdx.x * 4 + wid;
    int md5 = mtiles_d * 5, DOCU = md5 * 80;

    const ushort_t* x; const ushort_t* W; const float* bias;
    int Lout, mt, nt, ng;
    if (u < DOCU) {
        int nd = u / md5, r = u - nd * md5;
        mt = r / 5; nt = r - mt * 5;
        x = xd + (size_t)nd * xd_nstr; W = Wd; bias = bd; Lout = Lout_d;
        ng = 16 + nd;
    } else {
        int v = u - DOCU, mq5 = mtiles_q * 5;
        int nq = v / mq5, r = v - nq * mq5;
        mt = r / 5; nt = r - mt * 5;
        x = xq + (size_t)nq * xq_nstr; W = Wq; bias = bq; Lout = Lout_q;
        ng = nq;
    }
    int l0 = mt * 64;
    int lrow = lane & 15, quad = lane >> 4;

    // A staging source: lane covers (row = d*16 + lane/4, slot = lane%4),
    // source slot pre-swizzled: s ^ ((row>>1)&3) == s ^ ((lane>>3)&3).
    const ushort_t* gMain = x + (size_t)(l0 + (lane >> 2)) * CP
                              + ((lane & 3) ^ ((lane >> 3) & 3)) * 8;
    // row 64 (tap overlap): lanes 0-3, slots 0-3 ((64>>1)&3 == 0, no swizzle)
    const ushort_t* gXtra = x + (size_t)(l0 + 64) * CP + lane * 8;

    // B fragment-packed: this wave's 4 n-subtiles start at g = nt*4.
    const ushort_t* Bw = W + (size_t)(nt * 4) * 512 + lane * 8;

    // A-fragment swizzled byte offsets (fixed per thread)
    int offA[2][4];
#pragma unroll
    for (int t = 0; t < 2; t++)
#pragma unroll
        for (int ms = 0; ms < 4; ms++) {
            int r = ms * 16 + lrow + t;
            offA[t][ms] = r * 64 + ((quad ^ ((r >> 1) & 3)) << 4);
        }

    floatx4 acc[4][4];
#pragma unroll
    for (int i = 0; i < 4; i++)
#pragma unroll
        for (int j = 0; j < 4; j++) acc[i][j] = (floatx4){0.f, 0.f, 0.f, 0.f};

    char* lb0 = &Abuf[wid][0][0];

    auto STAGE = [&](int cc, int slot) {          // 5 vmem instrs per wave
        char* lb = lb0 + slot * 4160;
        const ushort_t* gs = gMain + cc * 32;
        async_copy16(gs, lb);
        async_copy16(gs + (size_t)16 * CP, lb + 1024);
        async_copy16(gs + (size_t)32 * CP, lb + 2048);
        async_copy16(gs + (size_t)48 * CP, lb + 3072);
        if (lane < 4) async_copy16(gXtra + cc * 32, lb + 4096);
    };

    // prologue: stage chunks 0,1 into slots 0,1
    STAGE(0, 0);
    STAGE(1, 1);

    for (int c = 0; c < CH; c++) {
        // retire DMA(c); keep newer prefetches in flight
        if (c == 0) asm volatile("s_waitcnt vmcnt(5)" ::: "memory");
        else        asm volatile("s_waitcnt vmcnt(8)" ::: "memory");
        __builtin_amdgcn_sched_barrier(0);

        bf16x8 bf[2][4];
#pragma unroll
        for (int t = 0; t < 2; t++)
#pragma unroll
            for (int ns = 0; ns < 4; ns++)
                bf[t][ns] = *(const bf16x8*)(Bw + (size_t)((c * 2 + t) * 20 + ns) * 512);
        __builtin_amdgcn_sched_barrier(0x38F);    // pin VMEM order: B before DMA

        if (c + 2 < CH) STAGE(c + 2, (c + 2) % 3);

        const char* ab = lb0 + (c % 3) * 4160;
        __builtin_amdgcn_s_setprio(1);
#pragma unroll
        for (int t = 0; t < 2; t++) {
            bf16x8 af[4];
#pragma unroll
            for (int ms = 0; ms < 4; ms++)
                af[ms] = *(const bf16x8*)(ab + offA[t][ms]);
#pragma unroll
            for (int ms = 0; ms < 4; ms++)
#pragma unroll
                for (int ns = 0; ns < 4; ns++)
                    acc[ms][ns] = __builtin_amdgcn_mfma_f32_16x16x32_bf16(
                        af[ms], bf[t][ns], acc[ms][ns], 0, 0, 0);
        }
        __builtin_amdgcn_s_setprio(0);
    }

    // epilogue: transposed store yt2[n][o][l]
    ushort_t* yp = yt + (size_t)ng * (320 * 488);
#pragma unroll
    for (int ns = 0; ns < 4; ns++) {
        int o = nt * 64 + ns * 16 + lrow;
        if (o >= 300) continue;
        float bo = bias[o];
        ushort_t* orow = yp + (size_t)o * 488;
#pragma unroll
        for (int ms = 0; ms < 4; ms++) {
            int l = l0 + ms * 16 + quad * 4;
            if (l + 3 < Lout) {
                ushort4 v;
                v.x = f2b(tanhf(acc[ms][ns][0] + bo));
                v.y = f2b(tanhf(acc[ms][ns][1] + bo));
                v.z = f2b(tanhf(acc[ms][ns][2] + bo));
                v.w = f2b(tanhf(acc[ms][ns][3] + bo));
                *(ushort4*)&orow[l] = v;
            } else {
#pragma unroll
                for (int r = 0; r < 4; r++)
                    if (l + r < Lout) orow[l + r] = f2b(tanhf(acc[ms][ns][r] + bo));
            }
        }
    }
}

// ---------------------------------------------------------------------------
// g0 top-k: wave-per-row radix select, k=300 of L=1024 contiguous bf16.
// ---------------------------------------------------------------------------
__global__ __launch_bounds__(256) void topk_g0_kernel(
    const ushort_t* __restrict__ src, int CC, long long s_n,
    ushort_t* __restrict__ out, long long o_n, long long o_c)
{
    __shared__ uint hist[4][257];

    int tid = threadIdx.x, wid = tid >> 6, lane = tid & 63;
    int row = blockIdx.x * 4 + wid;
    int n = row / CC, c = row - n * CC;
    const ushort_t* sp = src + (size_t)n * s_n + (size_t)c * 1024;

    // ---- load 16 elements/lane (2 x 16B, wave reads 2KB contiguous) ----
    const uint* sp32 = (const uint*)(sp + (size_t)lane * 16);
    uint pk[8];
    {
        uint4 va = *(const uint4*)sp32;
        uint4 vb = *(const uint4*)(sp32 + 4);
        pk[0] = va.x; pk[1] = va.y; pk[2] = va.z; pk[3] = va.w;
        pk[4] = vb.x; pk[5] = vb.y; pk[6] = vb.z; pk[7] = vb.w;
    }
    uint key[16];
#pragma unroll
    for (int i = 0; i < 8; i++) {
        uint w = pk[i];
        uint s = w & 0x80008000u;
        w ^= 0x80008000u | ((s >> 15) * 0x7fffu);   // packed kmap16
        key[2 * i] = w & 0xffffu;
        key[2 * i + 1] = w >> 16;
    }

    uint* hg = hist[wid];
    uint rem = 300, bsel = 0, T = 0;

#pragma unroll
    for (int round = 0; round < 2; round++) {
#pragma unroll
        for (int t = 0; t < 4; t++) hg[lane + t * 64] = 0;
        __builtin_amdgcn_sched_barrier(0);
        if (round == 0) {
#pragma unroll
            for (int e = 0; e < 16; e++) atomicAdd(&hg[key[e] >> 8], 1u);
        } else {
#pragma unroll
            for (int e = 0; e < 16; e++)
                if ((key[e] >> 8) == bsel) atomicAdd(&hg[key[e] & 255u], 1u);
        }
        __builtin_amdgcn_sched_barrier(0);
        uint hv[4], Sr = 0;
#pragma unroll
        for (int t = 0; t < 4; t++) { hv[t] = hg[lane * 4 + t]; Sr += hv[t]; }
        uint suf = Sr;
#pragma unroll
        for (int off = 1; off < 64; off <<= 1) {
            uint u = __shfl_down(suf, off);
            if (lane + off < 64) suf += u;
        }
        uint acc = suf - Sr;
        uint found = 0;
#pragma unroll
        for (int t = 3; t >= 0; t--) {
            uint h = hv[t];
            if (!found && acc < rem && acc + h >= rem)
                found = ((uint)(lane * 4 + t) << 16) | (rem - acc);
            acc += h;
        }
#pragma unroll
        for (int off = 1; off < 64; off <<= 1) found |= __shfl_xor(found, off);
        if (round == 0) {
            bsel = found >> 16;
            rem = found & 0xffffu;
        } else {
            T = (bsel << 8) | (found >> 16);
            rem = found & 0xffffu;
        }
        __builtin_amdgcn_sched_barrier(0);
    }

    uint gtc = 0, eqc = 0;
#pragma unroll
    for (int e = 0; e < 16; e++) {
        gtc += (key[e] > T) ? 1u : 0u;
        eqc += (key[e] == T) ? 1u : 0u;
    }
    uint pack = (gtc << 16) | eqc, incl = pack;
#pragma unroll
    for (int off = 1; off < 64; off <<= 1) {
        uint u = __shfl_up(incl, off);
        if (lane >= off) incl += u;
    }
    uint excl = incl - pack;
    uint gt_b = excl >> 16, eq_b = excl & 0xffffu;

    ushort_t* dp = out + (size_t)n * o_n + (size_t)c * o_c;
#pragma unroll
    for (int e = 0; e < 16; e++) {
        uint kk = key[e];
        if (kk > T) {
            uint pos = gt_b + (eq_b < rem ? eq_b : rem);
            dp[pos] = kinv16(kk);
            gt_b++;
        } else if (kk == T) {
            if (eq_b < rem) dp[gt_b + eq_b] = kinv16(kk);
            eq_b++;
        }
    }
}

// ---------------------------------------------------------------------------
// Multi-column top-k for the p-stages.  Block = one n x 32 channels.
// ---------------------------------------------------------------------------
__global__ __launch_bounds__(256) void topk_cols_kernel(
    const ushort_t* __restrict__ yt2,
    int Lq, int Ld, int kq, int kd,
    ushort_t* __restrict__ qg, int qoff,
    ushort_t* __restrict__ dg, int doff,
    ushort_t* __restrict__ pq, long long pq_nstr,
    ushort_t* __restrict__ pd, long long pd_nstr)
{
    __shared__ __align__(16) ushort_t xin[32][488];   // 31232 B
    __shared__ __align__(16) uint hist[32 * 257];     // 32896 B, reused as otile
    ushort_t* otile = (ushort_t*)hist;                // [pos][32] halves

    int cg = blockIdx.x, n = blockIdx.y;
    int c0 = cg * 32;
    bool isq = (n < 16);
    int L = isq ? Lq : Ld;
    int k = isq ? kq : kd;
    int nd = isq ? n : n - 16;
    int tid = threadIdx.x;

    const ushort_t* src = yt2 + (size_t)n * (320 * 488) + (size_t)c0 * 488;
    for (int i = tid; i < 32 * 61; i += 256) {
        int j = i / 61, s = i - j * 61;
        *(uint4*)&xin[j][s * 8] = *(const uint4*)&src[(size_t)j * 488 + s * 8];
    }
    __syncthreads();

    int g = tid >> 3, r = tid & 7;
    uint* hg = &hist[g * 257];
    bool cval = (c0 + g) < 300;
    int S = (L + 7) >> 3;
    int llo = r * S, lhi = llo + S;
    if (lhi > L) lhi = L;
    if (llo > L) llo = L;

    uint rem = (uint)k;
    uint bsel = 0;
    uint Tt = 0;

#pragma unroll
    for (int round = 0; round < 2; round++) {
        for (int t = r; t < 256; t += 8) hg[t] = 0;
        for (int l = llo; l < lhi; l++) {
            uint key = cval ? kmap16(xin[g][l]) : 0x8000u;
            if (round == 0)
                atomicAdd(&hg[key >> 8], 1u);
            else if ((key >> 8) == bsel)
                atomicAdd(&hg[key & 255u], 1u);
        }
        uint hv[32];
        uint Sr = 0;
        int b0 = r * 32;
#pragma unroll
        for (int t = 0; t < 32; t++) { hv[t] = hg[b0 + t]; Sr += hv[t]; }
        uint suf = Sr;
#pragma unroll
        for (int off = 1; off < 8; off <<= 1) {
            uint u = __shfl_down(suf, off);
            if (r + off < 8) suf += u;
        }
        uint acc = suf - Sr;
        uint found = 0;
#pragma unroll
        for (int t = 31; t >= 0; t--) {
            uint h = hv[t];
            if (!found && acc < rem && acc + h >= rem)
                found = ((uint)(b0 + t) << 16) | (rem - acc);
            acc += h;
        }
#pragma unroll
        for (int off = 1; off < 8; off <<= 1) found |= __shfl_xor(found, off);
        if (round == 0) {
            bsel = found >> 16;
            rem = found & 0xffffu;
        } else {
            Tt = (bsel << 8) | (found >> 16);
            rem = found & 0xffffu;
        }
    }

    uint gtc = 0, eqc = 0;
    for (int l = llo; l < lhi; l++) {
        uint key = cval ? kmap16(xin[g][l]) : 0x8000u;
        gtc += (key > Tt) ? 1u : 0u;
        eqc += (key == Tt) ? 1u : 0u;
    }
    uint pack = (gtc << 16) | eqc, incl = pack;
#pragma unroll
    for (int off = 1; off < 8; off <<= 1) {
        uint u = __shfl_up(incl, off);
        if (r >= off) incl += u;
    }
    uint excl = incl - pack;
    uint gt_b = excl >> 16, eq_b = excl & 0xffffu;

    __syncthreads();                      // hist -> otile reuse

    for (int l = llo; l < lhi; l++) {
        uint key = cval ? kmap16(xin[g][l]) : 0x8000u;
        if (key > Tt) {
            uint pos = gt_b + (eq_b < rem ? eq_b : rem);
            otile[pos * 32 + g] = kinv16(key);
            gt_b++;
        } else if (key == Tt) {
            if (eq_b < rem) otile[(gt_b + eq_b) * 32 + g] = kinv16(key);
            eq_b++;
        }
    }
    __syncthreads();

    ushort_t* d1 = isq ? qg + ((size_t)nd * 480 + qoff) * 320 + c0
                       : dg + ((size_t)nd * 960 + doff) * 320 + c0;
    ushort_t* d2 = 0;
    if (isq) { if (pq) d2 = pq + (size_t)nd * pq_nstr + 4 * 320 + c0; }
    else     { if (pd) d2 = pd + (size_t)nd * pd_nstr + 4 * 320 + c0; }

    for (int i = tid; i < k * 8; i += 256) {
        int p = i >> 3, s = i & 7;
        ushort4 v = *(ushort4*)&otile[p * 32 + s * 4];
        *(ushort4*)&d1[(size_t)p * 320 + s * 4] = v;
        if (d2) *(ushort4*)&d2[(size_t)p * 320 + s * 4] = v;
    }
}

// ---------------------------------------------------------------------------
// qt GEMM: qtb[b,m,e] = bf16( sum_d qgb[b,m,d] * bwb[e,d] ).
// ---------------------------------------------------------------------------
__global__ __launch_bounds__(256) void qt_mfma_kernel(
    const ushort_t* __restrict__ qgb, const ushort_t* __restrict__ bwb,
    ushort_t* __restrict__ qtb)
{
    int mt = blockIdx.x, b = blockIdx.y;
    int tid = threadIdx.x, wid = tid >> 6, lane = tid & 63;
    int wn = wid * 80, lrow = lane & 15, quad = lane >> 4;

    const ushort_t* A = qgb + ((size_t)b * 480 + mt * 48 + lrow) * 320 + quad * 8;
    const ushort_t* B = bwb + (size_t)(wn + lrow) * 320 + quad * 8;

    floatx4 acc[3][5];
#pragma unroll
    for (int i = 0; i < 3; i++)
#pragma unroll
        for (int j = 0; j < 5; j++) acc[i][j] = (floatx4){0.f, 0.f, 0.f, 0.f};

#pragma unroll 5
    for (int c0 = 0; c0 < 320; c0 += 32) {
        bf16x8 af[3], bfr[5];
#pragma unroll
        for (int ms = 0; ms < 3; ms++)
            af[ms] = *(const bf16x8*)&A[(size_t)(ms * 16) * 320 + c0];
#pragma unroll
        for (int ns = 0; ns < 5; ns++)
            bfr[ns] = *(const bf16x8*)&B[(size_t)(ns * 16) * 320 + c0];
#pragma unroll
        for (int ms = 0; ms < 3; ms++)
#pragma unroll
            for (int ns = 0; ns < 5; ns++)
                acc[ms][ns] = __builtin_amdgcn_mfma_f32_16x16x32_bf16(
                    af[ms], bfr[ns], acc[ms][ns], 0, 0, 0);
    }

    ushort_t* out = qtb + ((size_t)b * 480 + mt * 48) * 320;
#pragma unroll
    for (int ms = 0; ms < 3; ms++)
#pragma unroll
        for (int ns = 0; ns < 5; ns++)
#pragma unroll
            for (int r = 0; r < 4; r++)
                out[(size_t)(ms * 16 + quad * 4 + r) * 320 + wn + ns * 16 + lrow] =
                    f2b(acc[ms][ns][r]);
}

// ---------------------------------------------------------------------------
// MFMA M-GEMM fused with pooling.
// ---------------------------------------------------------------------------
__global__ __launch_bounds__(256) void mpool_mfma_kernel(
    const ushort_t* __restrict__ qtb16, const ushort_t* __restrict__ dgb16,
    const float* __restrict__ bb, float* __restrict__ mp)
{
    __shared__ float pool[2 * 12 * 192];

    int jb = blockIdx.x;
    int qb = blockIdx.y;
    int n  = blockIdx.z;
    int b  = n & 15;

    int tid = threadIdx.x;
    int wid = tid >> 6, lane = tid & 63;
    int wm2 = wid >> 1;
    int wm = wm2 * 48, wn = (wid & 1) * 96;
    int lrow = lane & 15, quad = lane >> 4;

    const ushort_t* Abase = qtb16 + ((size_t)b * 480 + qb * 96 + wm) * 320 + quad * 8;
    const ushort_t* Bbase = dgb16 + ((size_t)n * 960 + jb * 192 + wn) * 320 + quad * 8;

    floatx4 acc[3][6];
#pragma unroll
    for (int i = 0; i < 3; i++)
#pragma unroll
        for (int j = 0; j < 6; j++) acc[i][j] = (floatx4){0.f, 0.f, 0.f, 0.f};

#pragma unroll 2
    for (int c0 = 0; c0 < 320; c0 += 32) {
        bf16x8 af[3], bfr[6];
#pragma unroll
        for (int mt = 0; mt < 3; mt++)
            af[mt] = *(const bf16x8*)&Abase[(size_t)(mt * 16 + lrow) * 320 + c0];
#pragma unroll
        for (int nt = 0; nt < 6; nt++)
            bfr[nt] = *(const bf16x8*)&Bbase[(size_t)(nt * 16 + lrow) * 320 + c0];
#pragma unroll
        for (int mt = 0; mt < 3; mt++)
#pragma unroll
            for (int nt = 0; nt < 6; nt++)
                acc[mt][nt] = __builtin_amdgcn_mfma_f32_16x16x32_bf16(
                    af[mt], bfr[nt], acc[mt][nt], 0, 0, 0);
    }

#pragma unroll
    for (int mt = 0; mt < 3; mt++) {
        int g = mt * 4 + quad;
#pragma unroll
        for (int nt = 0; nt < 6; nt++) {
            floatx4 a = acc[mt][nt];
            float rm = fmaxf(fmaxf(a[0], a[1]), fmaxf(a[2], a[3]));
            pool[(wm2 * 12 + g) * 192 + wn + nt * 16 + lrow] = rm;
        }
    }
    __syncthreads();

    if (tid < 64) {
        int qw = tid >> 3, jw = tid & 7;
        int slab = qw >> 2, w = qw & 3;
        float m = -INFINITY;
        const float* pp = &pool[(slab * 12 + w * 3) * 192 + jw * 24];
        for (int g = 0; g < 3; g++)
            for (int cc = 0; cc < 24; cc++)
                m = fmaxf(m, pp[g * 192 + cc]);
        float sig = 1.f / (1.f + expf(-(m + bb[0])));
        mp[(size_t)n * 1600 + (size_t)(qb * 8 + qw) * 40 + (jb * 8 + jw)] = sig;
    }
}

// ---------------------------------------------------------------------------
// Conv block, channel-parallel, atomicMax-merged (Y zeroed before launch).
// ---------------------------------------------------------------------------
#define OCG 10
__global__ __launch_bounds__(256) void convblock_atomic_kernel(
    const float* __restrict__ X, const float* __restrict__ w,
    const float* __restrict__ bias, uint* __restrict__ Y)
{
    __shared__ float xp[48 * 48];
    __shared__ float ys[47 * 47];
    __shared__ float t1[40 * 47];
    __shared__ float outacc[1600];

    int n = blockIdx.x, t = threadIdx.x;
    int oc0 = blockIdx.y * OCG;
    const float* xn = X + (size_t)n * 1600;
    for (int i = t; i < 48 * 48; i += 256) {
        int r = i / 48, c = i - r * 48;
        int rr = r - 4, cc = c - 4;
        xp[i] = (rr >= 0 && rr < 40 && cc >= 0 && cc < 40) ? xn[rr * 40 + cc] : 0.f;
    }
    for (int i = t; i < 1600; i += 256) outacc[i] = 0.f;
    __syncthreads();

    for (int oc = oc0; oc < oc0 + OCG; oc++) {
        float w00 = w[oc * 4 + 0], w01 = w[oc * 4 + 1];
        float w10 = w[oc * 4 + 2], w11 = w[oc * 4 + 3];
        float bo = bias[oc];
        for (int i = t; i < 47 * 47; i += 256) {
            int r = i / 47, c = i - r * 47;
            float v = xp[r * 48 + c] * w00 + xp[r * 48 + c + 1] * w01
                    + xp[(r + 1) * 48 + c] * w10 + xp[(r + 1) * 48 + c + 1] * w11 + bo;
            ys[i] = 1.f / (1.f + expf(-v));
        }
        __syncthreads();
        for (int i = t; i < 40 * 47; i += 256) {
            int r = i / 47, c = i - r * 47;
            int s = (47 * r) / 40, e = (47 * (r + 1) + 39) / 40;
            float m = ys[s * 47 + c];
            for (int x = s + 1; x < e; x++) m = fmaxf(m, ys[x * 47 + c]);
            t1[i] = m;
        }
        __syncthreads();
        for (int i = t; i < 1600; i += 256) {
            int r = i / 40, c = i - r * 40;
            int s = (47 * c) / 40, e = (47 * (c + 1) + 39) / 40;
            float m = t1[r * 47 + s];
            for (int x = s + 1; x < e; x++) m = fmaxf(m, t1[r * 47 + x]);
            outacc[i] = fmaxf(outacc[i], m);
        }
        __syncthreads();
    }
    for (int i = t; i < 1600; i += 256)
        atomicMax(&Y[(size_t)n * 1600 + i], __float_as_uint(outacc[i]));
}

// ---------------------------------------------------------------------------
// Head
// ---------------------------------------------------------------------------
__global__ __launch_bounds__(64) void head_kernel(
    const float* __restrict__ feat, const float* __restrict__ lw,
    const float* __restrict__ lb, float* __restrict__ out)
{
    __shared__ float hs[40];
    int n = blockIdx.x, t = threadIdx.x;
    const float* f = feat + (size_t)n * 1600;
    if (t < 40) {
        float a = 0.f;
        for (int j = 0; j < 40; j++) a += f[t * 40 + j] * lw[j];
        hs[t] = 1.f / (1.f + expf(-(a + lb[0])));
    }
    __syncthreads();
    if (t == 0) {
        float a = 0.f;
        for (int i = 0; i < 40; i++) a += hs[i] * lw[i];
        out[n] = 1.f / (1.f + expf(-(a + lb[0])));
    }
}

// ---------------------------------------------------------------------------
extern "C" void kernel_launch(void* const* d_in, const int* in_sizes, int n_in,
                              void* d_out, int out_size, void* d_ws, size_t ws_size,
                              hipStream_t stream) {
    const float* query    = (const float*)d_in[0];
    const float* pos_doc  = (const float*)d_in[1];
    const float* neg_docs = (const float*)d_in[2];
    const float* qw1 = (const float*)d_in[3];  const float* qb1 = (const float*)d_in[4];
    const float* qw2 = (const float*)d_in[5];  const float* qb2 = (const float*)d_in[6];
    const float* qw3 = (const float*)d_in[7];  const float* qb3 = (const float*)d_in[8];
    const float* dw1 = (const float*)d_in[9];  const float* db1 = (const float*)d_in[10];
    const float* dw2 = (const float*)d_in[11]; const float* db2 = (const float*)d_in[12];
    const float* dw3 = (const float*)d_in[13]; const float* db3 = (const float*)d_in[14];
    const float* bw  = (const float*)d_in[15]; const float* bb  = (const float*)d_in[16];
    const float* mw1 = (const float*)d_in[17]; const float* mb1 = (const float*)d_in[18];
    const float* mw2 = (const float*)d_in[19]; const float* mb2 = (const float*)d_in[20];
    const float* mw3 = (const float*)d_in[21]; const float* mb3 = (const float*)d_in[22];
    const float* lw  = (const float*)d_in[23]; const float* lb  = (const float*)d_in[24];

    float* ws = (float*)d_ws;
    // ---- layout (float offsets) ----
    ushort_t* qw1b  = (ushort_t*)(ws + 0);          // 320*2048 bf16
    ushort_t* qw2b  = (ushort_t*)(ws + 327680);     // 320*640
    ushort_t* qw3b  = (ushort_t*)(ws + 430080);
    ushort_t* dw1b  = (ushort_t*)(ws + 532480);
    ushort_t* dw2b  = (ushort_t*)(ws + 860160);
    ushort_t* dw3b  = (ushort_t*)(ws + 962560);
    ushort_t* bwb   = (ushort_t*)(ws + 1064960);    // 320*320
    ushort_t* qgb16 = (ushort_t*)(ws + 1116160);    // (16,480,320)
    ushort_t* dgb16 = (ushort_t*)(ws + 2344960);    // (80,960,320)
    ushort_t* yt    = (ushort_t*)(ws + 14632960);   // (96,320,488)  o-major
    ushort_t* qxb   = (ushort_t*)(ws + 22128640);   // (16,264,1024)
    ushort_t* p1q   = (ushort_t*)(ws + 22128640);   // (16,200,320)
    ushort_t* p2q   = (ushort_t*)(ws + 22640640);   // (16,104,320)
    ushort_t* dxb   = (ushort_t*)(ws + 24291328);   // (80,520,1024)
    ushort_t* p1d   = (ushort_t*)(ws + 24291328);   // (80,360,320)
    ushort_t* p2d   = (ushort_t*)(ws + 28899328);   // (80,200,320)
    ushort_t* qtb16 = (ushort_t*)(ws + 31459328);   // (16,480,320)
    float*    mp    = ws + 32688128;                // (80,40,40)
    float*    ya    = ws + 32816128;                // (80,40,40)
    float*    yb    = ws + 32944128;                // (80,40,40)
    float*    yc    = ws + 33072128;                // (80,40,40)

    // ---- weight prep (MFMA-fragment-packed layout) ----
    prep_w2_kernel<<<1280, 256, 0, stream>>>(qw1, qw1b, 1024, 1024);
    prep_w2_kernel<<<400, 256, 0, stream>>>(qw2, qw2b, 300, 320);
    prep_w2_kernel<<<400, 256, 0, stream>>>(qw3, qw3b, 300, 320);
    prep_w2_kernel<<<1280, 256, 0, stream>>>(dw1, dw1b, 1024, 1024);
    prep_w2_kernel<<<400, 256, 0, stream>>>(dw2, dw2b, 300, 320);
    prep_w2_kernel<<<400, 256, 0, stream>>>(dw3, dw3b, 300, 320);
    prep_bw_kernel<<<400, 256, 0, stream>>>(bw, bwb);

    // ---- input convert to padded bf16 ----
    {
        dim3 g(264, 16);
        x_pad_bf16_kernel<<<g, 256, 0, stream>>>(query, nullptr, 0,
                                                 239LL * 1024, 239, qxb, 264);
    }
    {
        dim3 g(520, 80);
        x_pad_bf16_kernel<<<g, 256, 0, stream>>>(pos_doc, neg_docs, 16,
                                                 479LL * 1024, 479, dxb, 520);
    }

    // ---- g0 top-ks (wave-per-row radix select) ----
    topk_g0_kernel<<<(16 * 239) / 4, 256, 0, stream>>>(
        qxb + 4 * 1024, 239, 264LL * 1024, qgb16, 480LL * 320, 320);
    topk_g0_kernel<<<(80 * 479) / 4, 256, 0, stream>>>(
        dxb + 4 * 1024, 479, 520LL * 1024, dgb16, 960LL * 320, 320);

    // ---- conv1 (barrier-free wave-pipelined, transposed output) ----
    // units: doc 8mt*5nt*80 + q 4mt*5nt*16 = 3520 -> 880 blocks
    conv_wave_kernel<1024><<<880, 256, 0, stream>>>(
        qxb, 264LL * 1024, dxb, 520LL * 1024,
        qw1b, dw1b, qb1, db1, 246, 486, 4, 8, yt);

    // ---- zero conv2/3 input pads ----
    hipMemsetAsync(p1q, 0, 16 * 200 * 320 * 2, stream);
    hipMemsetAsync(p2q, 0, 16 * 104 * 320 * 2, stream);
    hipMemsetAsync(p1d, 0, (size_t)80 * 360 * 320 * 2, stream);
    hipMemsetAsync(p2d, 0, (size_t)80 * 200 * 320 * 2, stream);
    // ---- zero conv-block outputs (atomicMax targets) ----
    hipMemsetAsync(ya, 0, 80 * 1600 * 4, stream);
    hipMemsetAsync(yb, 0, 80 * 1600 * 4, stream);
    hipMemsetAsync(yc, 0, 80 * 1600 * 4, stream);

    // ---- p1 top-ks (multi-column, line-coalesced) ----
    {
        dim3 g(10, 96);
        topk_cols_kernel<<<g, 256, 0, stream>>>(
            yt, 246, 486, 160, 320,
            qgb16, 239, dgb16, 479,
            p1q, 200LL * 320, p1d, 360LL * 320);
    }

    // ---- conv2: doc 6mt*5*80 + q 3mt*5*16 = 2640 -> 660 blocks ----
    conv_wave_kernel<320><<<660, 256, 0, stream>>>(
        p1q, 200LL * 320, p1d, 360LL * 320,
        qw2b, dw2b, qb2, db2, 167, 327, 3, 6, yt);

    // ---- p2 top-ks ----
    {
        dim3 g(10, 96);
        topk_cols_kernel<<<g, 256, 0, stream>>>(
            yt, 167, 327, 80, 160,
            qgb16, 399, dgb16, 799,
            p2q, 104LL * 320, p2d, 200LL * 320);
    }

    // ---- conv3: doc 3mt*5*80 + q 2mt*5*16 = 1360 -> 340 blocks ----
    conv_wave_kernel<320><<<340, 256, 0, stream>>>(
        p2q, 104LL * 320, p2d, 200LL * 320,
        qw3b, dw3b, qb3, db3, 87, 167, 2, 3, yt);

    // ---- p3 top-ks (k=1) ----
    {
        dim3 g(10, 96);
        topk_cols_kernel<<<g, 256, 0, stream>>>(
            yt, 87, 167, 1, 1,
            qgb16, 479, dgb16, 959,
            nullptr, 0, nullptr, 0);
    }

    // ---- qt GEMM + fused similarity/pool ----
    {
        dim3 g(10, 16);
        qt_mfma_kernel<<<g, 256, 0, stream>>>(qgb16, bwb, qtb16);
    }
    {
        dim3 g(5, 5, 80);
        mpool_mfma_kernel<<<g, 256, 0, stream>>>(qtb16, dgb16, bb, mp);
    }

    // ---- conv blocks (channel-parallel, atomicMax-merged) + head ----
    {
        dim3 g(80, 5);
        convblock_atomic_kernel<<<g, 256, 0, stream>>>(mp, mw1, mb1, (uint*)ya);
        convblock_atomic_kernel<<<g, 256, 0, stream>>>(ya, mw2, mb2, (uint*)yb);
        convblock_atomic_kernel<<<g, 256, 0, stream>>>(yb, mw3, mb3, (uint*)yc);
    }
    head_kernel<<<80, 64, 0, stream>>>(yc, lw, lb, (float*)d_out);
}